// Round 9
// baseline (409.990 us; speedup 1.0000x reference)
//
#include <hip/hip_runtime.h>

#define Bsz  4
#define Tseq 2048
#define Cdim 512
#define Hn   8
#define Dh   64
#define BT   8192     // Bsz*Tseq tokens
#define NQKV 1536
#define NEG_BIG (-1e30f)

typedef __attribute__((ext_vector_type(8))) short bf16x8;  // 8 bf16 = 4 VGPRs
typedef __attribute__((ext_vector_type(4))) short bf16x4;  // 4 bf16 = 2 VGPRs
typedef __attribute__((ext_vector_type(4))) float f32x4;

__device__ __forceinline__ float b2f(short s) {
    unsigned u = ((unsigned)(unsigned short)s) << 16;
    float f; __builtin_memcpy(&f, &u, 4); return f;
}
__device__ __forceinline__ short f2b(float f) {
    unsigned u; __builtin_memcpy(&u, &f, 4);
    u = (u + 0x7fffu + ((u >> 16) & 1u)) >> 16;   // RNE
    return (short)u;
}

// ---------------- weight transpose + bf16 cast: W[c][n] (fp32) -> Wt[n][c] (bf16) ----------------
__global__ __launch_bounds__(256) void k_transpose(const float* __restrict__ wq, const float* __restrict__ wk,
                                                   const float* __restrict__ wv, const float* __restrict__ wff,
                                                   short* __restrict__ wqkvt, short* __restrict__ wfft) {
    int idx = blockIdx.x * 256 + threadIdx.x;     // grid covers 1536*512 + 512*512 = 1048576 exactly
    if (idx < NQKV * Cdim) {
        int n = idx >> 9, c = idx & 511;
        int proj = n >> 9, nn = n & 511;
        int h = nn >> 6, d = nn & 63;
        const float* w = (proj == 0) ? wq : (proj == 1 ? wk : wv);
        wqkvt[idx] = f2b(w[(h * Cdim + c) * Dh + d]);
    } else {
        int i2 = idx - NQKV * Cdim;
        int n = i2 >> 9, c = i2 & 511;
        wfft[i2] = f2b(wff[c * Cdim + n]);
    }
}

// ---------------- LayerNorm: fp32 in, bf16 out ----------------
__global__ __launch_bounds__(256) void k_ln(const float* __restrict__ x, const float* __restrict__ g,
                                            const float* __restrict__ b, short* __restrict__ out) {
    int row  = blockIdx.x * 4 + (threadIdx.x >> 6);   // one wave per token row
    int lane = threadIdx.x & 63;
    const f32x4 a0 = *(const f32x4*)(x + row * Cdim + lane * 8);
    const f32x4 a1 = *(const f32x4*)(x + row * Cdim + lane * 8 + 4);
    float v[8] = {a0[0], a0[1], a0[2], a0[3], a1[0], a1[1], a1[2], a1[3]};
    float s = 0.f, sq = 0.f;
#pragma unroll
    for (int i = 0; i < 8; i++) { s += v[i]; sq += v[i] * v[i]; }
#pragma unroll
    for (int off = 1; off < 64; off <<= 1) { s += __shfl_xor(s, off); sq += __shfl_xor(sq, off); }
    float mean = s * (1.f / 512.f);
    float var  = sq * (1.f / 512.f) - mean * mean;
    float rstd = rsqrtf(var + 1e-5f);
    const f32x4 g0 = *(const f32x4*)(g + lane * 8);
    const f32x4 g1 = *(const f32x4*)(g + lane * 8 + 4);
    const f32x4 b0 = *(const f32x4*)(b + lane * 8);
    const f32x4 b1 = *(const f32x4*)(b + lane * 8 + 4);
    float gg[8] = {g0[0], g0[1], g0[2], g0[3], g1[0], g1[1], g1[2], g1[3]};
    float bb[8] = {b0[0], b0[1], b0[2], b0[3], b1[0], b1[1], b1[2], b1[3]};
    bf16x8 o;
#pragma unroll
    for (int i = 0; i < 8; i++) o[i] = f2b((v[i] - mean) * rstd * gg[i] + bb[i]);
    *(bf16x8*)(out + row * Cdim + lane * 8) = o;
}

// ---------------- QKV GEMM: [8192,512] x Wt[1536,512], all bf16 ----------------
__global__ __launch_bounds__(256) void k_gemm_qkv(const short* __restrict__ A, const short* __restrict__ Wt,
                                                  short* __restrict__ q, short* __restrict__ k,
                                                  short* __restrict__ vt) {
    const int wave = threadIdx.x >> 6, lane = threadIdx.x & 63;
    const int quad = lane >> 4, l15 = lane & 15;
    const int m0 = blockIdx.x * 256 + wave * 64;
    const int n0 = blockIdx.y * 64;
    f32x4 acc[4][4];
#pragma unroll
    for (int i = 0; i < 4; i++)
#pragma unroll
        for (int j = 0; j < 4; j++) acc[i][j] = (f32x4){0.f, 0.f, 0.f, 0.f};
    const short* Ab = A  + (m0 + l15) * Cdim + quad * 8;
    const short* Bb = Wt + (n0 + l15) * Cdim + quad * 8;
#pragma unroll 2
    for (int ks = 0; ks < 16; ks++) {
        bf16x8 a[4], w[4];
#pragma unroll
        for (int mt = 0; mt < 4; mt++) a[mt] = *(const bf16x8*)(Ab + mt * 16 * Cdim + ks * 32);
#pragma unroll
        for (int nt = 0; nt < 4; nt++) w[nt] = *(const bf16x8*)(Bb + nt * 16 * Cdim + ks * 32);
#pragma unroll
        for (int mt = 0; mt < 4; mt++)
#pragma unroll
            for (int nt = 0; nt < 4; nt++)
                acc[mt][nt] = __builtin_amdgcn_mfma_f32_16x16x32_bf16(a[mt], w[nt], acc[mt][nt], 0, 0, 0);
    }
    // epilogue: whole block lies in one projection + one head (n-tile = 64 = head size)
    const int proj = n0 >> 9;
    const int hh   = (n0 & 511) >> 6;
#pragma unroll
    for (int mt = 0; mt < 4; mt++) {
#pragma unroll
        for (int r = 0; r < 4; r++) {
            int t  = m0 + mt * 16 + quad * 4 + r;
            int bi = t >> 11, tt = t & 2047;
#pragma unroll
            for (int nt = 0; nt < 4; nt++) {
                int d = nt * 16 + l15;
                short val = f2b(acc[mt][nt][r]);
                if (proj == 0)      q [((bi * Hn + hh) * Tseq + tt) * Dh + d] = val;
                else if (proj == 1) k [((bi * Hn + hh) * Tseq + tt) * Dh + d] = val;
                else                vt[((bi * Hn + hh) * Dh + d) * Tseq + tt] = val;
            }
        }
    }
}

// ---------------- causal flash attention, v7: split-K + fully register-resident loop ----------------
// S^T = mfma(K,Q): lane holds (s=quad*4+r, q=l15) -> per-lane softmax (2 shuffles/reduce).
// P^T registers (k=quad*4+r, n=l15) ARE the B-operand of mfma_f32_16x16x16bf16_1k;
// V^T rows from vtb[d][s] are its A-operand (m=d=l15, k=s=quad*4+j, 8B loads).
// PV computes O^T (d=dt*16+quad*4+r, q=l15): alpha/l rescale is per-lane. ZERO in-loop
// LDS / fences / broadcast-shuffles -> compiler can pipeline K/V loads across tiles.
__global__ __launch_bounds__(256) void k_attn(const short* __restrict__ qb, const short* __restrict__ kb,
                                              const short* __restrict__ vtb, const float* __restrict__ x,
                                              float* __restrict__ out1) {
    const int wave = threadIdx.x >> 6, lane = threadIdx.x & 63;
    const int quad = lane >> 4, l15 = lane & 15;
    const int bh = blockIdx.y;
    const int qtile = 127 - blockIdx.x;         // heavy-first (LPT)
    const int q0 = qtile * 16;
    const short* Q = qb  + bh * Tseq * Dh;
    const short* K = kb  + bh * Tseq * Dh;
    const short* V = vtb + bh * Dh * Tseq;      // [d][s]

    __shared__ float ldsO[4][16][72];           // combine zones, pad 72 (4-way max on b128 store)
    __shared__ float ldsM[4][16];
    __shared__ float ldsL[4][16];

    bf16x8 qa[2];
#pragma unroll
    for (int c = 0; c < 2; c++)
        qa[c] = *(const bf16x8*)(Q + (q0 + l15) * Dh + c * 32 + quad * 8);

    f32x4 o[4];                                 // O^T: d = dt*16 + quad*4 + r, q = l15
#pragma unroll
    for (int i = 0; i < 4; i++) o[i] = (f32x4){0.f, 0.f, 0.f, 0.f};
    float m_i = NEG_BIG, l_i = 0.f;             // per-lane: q = q0 + l15

    const float sc = 0.125f * 1.44269504089f;   // scale * log2(e): softmax in exp2 domain
    const int nkt = (q0 + 79) >> 6;             // 64-key tiles covering keys <= q0+15
    for (int kt = wave; kt < nkt; kt += 4) {    // strided split-K across the 4 waves
        const int s0 = kt * 64;
        // S^T: 4 tiles of (16s x 16q); lane holds s=s0+nt*16+quad*4+r, q=q0+l15
        f32x4 st[4];
#pragma unroll
        for (int nt = 0; nt < 4; nt++) {
            bf16x8 k0 = *(const bf16x8*)(K + (s0 + nt * 16 + l15) * Dh + quad * 8);
            bf16x8 k1 = *(const bf16x8*)(K + (s0 + nt * 16 + l15) * Dh + 32 + quad * 8);
            f32x4 z = (f32x4){0.f, 0.f, 0.f, 0.f};
            z = __builtin_amdgcn_mfma_f32_16x16x32_bf16(k0, qa[0], z, 0, 0, 0);
            z = __builtin_amdgcn_mfma_f32_16x16x32_bf16(k1, qa[1], z, 0, 0, 0);
            st[nt] = z;
        }
        const int qq = q0 + l15;
        if (s0 + 63 > q0) {                     // wave-uniform: only causal-boundary tiles mask
#pragma unroll
            for (int nt = 0; nt < 4; nt++)
#pragma unroll
                for (int r = 0; r < 4; r++) {
                    int s = s0 + nt * 16 + quad * 4 + r;
                    st[nt][r] = (s > qq) ? NEG_BIG : st[nt][r] * sc;
                }
        } else {
#pragma unroll
            for (int nt = 0; nt < 4; nt++)
#pragma unroll
                for (int r = 0; r < 4; r++) st[nt][r] *= sc;
        }
        // per-lane online softmax (q=l15): in-lane 16-way + cross-quad xor16/xor32.
        // First tile of wave w has s0=64w <= q0 -> mx finite before any masked tile.
        float mx = fmaxf(fmaxf(fmaxf(st[0][0], st[0][1]), fmaxf(st[0][2], st[0][3])),
                         fmaxf(fmaxf(st[1][0], st[1][1]), fmaxf(st[1][2], st[1][3])));
        mx = fmaxf(mx, fmaxf(fmaxf(fmaxf(st[2][0], st[2][1]), fmaxf(st[2][2], st[2][3])),
                             fmaxf(fmaxf(st[3][0], st[3][1]), fmaxf(st[3][2], st[3][3]))));
        mx = fmaxf(mx, __shfl_xor(mx, 16));
        mx = fmaxf(mx, __shfl_xor(mx, 32));
        float mn    = fmaxf(m_i, mx);
        float alpha = __builtin_amdgcn_exp2f(m_i - mn);
        m_i = mn;
        float rs = 0.f;
        bf16x4 pk[4];                           // P^T: B-operand frags for 16x16x16 (k=quad*4+r)
#pragma unroll
        for (int nt = 0; nt < 4; nt++) {
#pragma unroll
            for (int r = 0; r < 4; r++) {
                float p = __builtin_amdgcn_exp2f(st[nt][r] - mn);   // masked -> 0
                rs += p;
                pk[nt][r] = f2b(p);
            }
        }
        rs += __shfl_xor(rs, 16);
        rs += __shfl_xor(rs, 32);
        l_i = l_i * alpha + rs;
        // rescale O^T: alpha is per-lane (q=l15) -- no shuffles
#pragma unroll
        for (int dt = 0; dt < 4; dt++)
#pragma unroll
            for (int r = 0; r < 4; r++) o[dt][r] *= alpha;
        // PV: O^T += V^T_frag(A) x P^T(B); V frag = 8B load from vtb[d][s]
#pragma unroll
        for (int nt = 0; nt < 4; nt++)
#pragma unroll
            for (int dt = 0; dt < 4; dt++) {
                bf16x4 vf = *(const bf16x4*)(V + (dt * 16 + l15) * Tseq + s0 + nt * 16 + quad * 4);
                o[dt] = __builtin_amdgcn_mfma_f32_16x16x16bf16_1k(vf, pk[nt], o[dt], 0, 0, 0);
            }
    }
    // ---- flash-combine of the 4 wave partials (all state per-lane at q=l15) ----
    if (quad == 0) ldsM[wave][l15] = m_i;
    __syncthreads();
    float Ml = fmaxf(fmaxf(ldsM[0][l15], ldsM[1][l15]), fmaxf(ldsM[2][l15], ldsM[3][l15]));
    float swl = __builtin_amdgcn_exp2f(m_i - Ml);            // empty wave: exp2(-1e30-M)=0
    l_i *= swl;
    if (quad == 0) ldsL[wave][l15] = l_i;
#pragma unroll
    for (int dt = 0; dt < 4; dt++) {
        f32x4 t = o[dt] * swl;
        *(f32x4*)&ldsO[wave][l15][dt * 16 + quad * 4] = t;   // O^T -> [q][d]
    }
    __syncthreads();
    // wave w sums rows 4w..4w+3; lane covers col d = lane (coalesced 256B stores)
    const int bi = bh >> 3, hh = bh & 7;
#pragma unroll
    for (int j = 0; j < 4; j++) {
        int row = wave * 4 + j;
        float L  = ldsL[0][row] + ldsL[1][row] + ldsL[2][row] + ldsL[3][row];
        float Of = ldsO[0][row][lane] + ldsO[1][row][lane] + ldsO[2][row][lane] + ldsO[3][row][lane];
        int t   = q0 + row;
        int idx = (bi * Tseq + t) * Cdim + hh * Dh + lane;
        out1[idx] = x[idx] + Of / L;
    }
}

// ---------------- FF GEMM: [8192,512] x Wt[512,512], fused bias+ReLU+residual, fp32 out ----------------
__global__ __launch_bounds__(256) void k_gemm_ff(const short* __restrict__ A, const short* __restrict__ Wt,
                                                 const float* __restrict__ bias, const float* __restrict__ res,
                                                 float* __restrict__ out) {
    const int wave = threadIdx.x >> 6, lane = threadIdx.x & 63;
    const int quad = lane >> 4, l15 = lane & 15;
    const int m0 = blockIdx.x * 256 + wave * 64;
    const int n0 = blockIdx.y * 64;
    f32x4 acc[4][4];
#pragma unroll
    for (int i = 0; i < 4; i++)
#pragma unroll
        for (int j = 0; j < 4; j++) acc[i][j] = (f32x4){0.f, 0.f, 0.f, 0.f};
    const short* Ab = A  + (m0 + l15) * Cdim + quad * 8;
    const short* Bb = Wt + (n0 + l15) * Cdim + quad * 8;
#pragma unroll 2
    for (int ks = 0; ks < 16; ks++) {
        bf16x8 a[4], w[4];
#pragma unroll
        for (int mt = 0; mt < 4; mt++) a[mt] = *(const bf16x8*)(Ab + mt * 16 * Cdim + ks * 32);
#pragma unroll
        for (int nt = 0; nt < 4; nt++) w[nt] = *(const bf16x8*)(Bb + nt * 16 * Cdim + ks * 32);
#pragma unroll
        for (int mt = 0; mt < 4; mt++)
#pragma unroll
            for (int nt = 0; nt < 4; nt++)
                acc[mt][nt] = __builtin_amdgcn_mfma_f32_16x16x32_bf16(a[mt], w[nt], acc[mt][nt], 0, 0, 0);
    }
#pragma unroll
    for (int mt = 0; mt < 4; mt++) {
#pragma unroll
        for (int r = 0; r < 4; r++) {
            int t = m0 + mt * 16 + quad * 4 + r;
#pragma unroll
            for (int nt = 0; nt < 4; nt++) {
                int n = n0 + nt * 16 + l15;
                float fv = acc[mt][nt][r] + bias[n];
                fv = fmaxf(fv, 0.f);
                out[t * Cdim + n] = res[t * Cdim + n] + fv;
            }
        }
    }
}

extern "C" void kernel_launch(void* const* d_in, const int* in_sizes, int n_in,
                              void* d_out, int out_size, void* d_ws, size_t ws_size,
                              hipStream_t stream) {
    const float* x   = (const float*)d_in[0];
    const float* wq  = (const float*)d_in[1];
    const float* wk  = (const float*)d_in[2];
    const float* wv  = (const float*)d_in[3];
    const float* wff = (const float*)d_in[4];
    const float* bff = (const float*)d_in[5];
    const float* g1  = (const float*)d_in[6];
    const float* b1  = (const float*)d_in[7];
    const float* g2  = (const float*)d_in[8];
    const float* b2  = (const float*)d_in[9];

    char* p = (char*)d_ws;                                  // ~50 MB total scratch
    short* wqkvt = (short*)p; p += (size_t)NQKV * Cdim * 2;
    short* wfft  = (short*)p; p += (size_t)Cdim * Cdim * 2;
    short* h1    = (short*)p; p += (size_t)BT * Cdim * 2;   // reused as h2 after attention
    short* qb    = (short*)p; p += (size_t)BT * Cdim * 2;
    short* kb    = (short*)p; p += (size_t)BT * Cdim * 2;
    short* vtb   = (short*)p; p += (size_t)BT * Cdim * 2;
    float* out1  = (float*)p; p += (size_t)BT * Cdim * 4;

    hipLaunchKernelGGL(k_transpose, dim3(4096),    dim3(256), 0, stream, wq, wk, wv, wff, wqkvt, wfft);
    hipLaunchKernelGGL(k_ln,        dim3(2048),    dim3(256), 0, stream, x, g1, b1, h1);
    hipLaunchKernelGGL(k_gemm_qkv,  dim3(32, 24),  dim3(256), 0, stream, h1, wqkvt, qb, kb, vtb);
    hipLaunchKernelGGL(k_attn,      dim3(128, 32), dim3(256), 0, stream, qb, kb, vtb, x, out1);
    hipLaunchKernelGGL(k_ln,        dim3(2048),    dim3(256), 0, stream, out1, g2, b2, h1);
    hipLaunchKernelGGL(k_gemm_ff,   dim3(32, 8),   dim3(256), 0, stream, h1, wfft, bff, out1, (float*)d_out);
}

// Round 10
// 356.360 us; speedup vs baseline: 1.1505x; 1.1505x over previous
//
#include <hip/hip_runtime.h>

#define Bsz  4
#define Tseq 2048
#define Cdim 512
#define Hn   8
#define Dh   64
#define BT   8192     // Bsz*Tseq tokens
#define NQKV 1536
#define NEG_BIG (-1e30f)

typedef __attribute__((ext_vector_type(8))) short bf16x8;  // 8 bf16 = 4 VGPRs
typedef __attribute__((ext_vector_type(4))) short bf16x4;  // 4 bf16 = 2 VGPRs
typedef __attribute__((ext_vector_type(4))) float f32x4;

__device__ __forceinline__ float b2f(short s) {
    unsigned u = ((unsigned)(unsigned short)s) << 16;
    float f; __builtin_memcpy(&f, &u, 4); return f;
}
__device__ __forceinline__ short f2b(float f) {
    unsigned u; __builtin_memcpy(&u, &f, 4);
    u = (u + 0x7fffu + ((u >> 16) & 1u)) >> 16;   // RNE
    return (short)u;
}

// ---------------- weight transpose + bf16 cast: W[c][n] (fp32) -> Wt[n][c] (bf16) ----------------
__global__ __launch_bounds__(256) void k_transpose(const float* __restrict__ wq, const float* __restrict__ wk,
                                                   const float* __restrict__ wv, const float* __restrict__ wff,
                                                   short* __restrict__ wqkvt, short* __restrict__ wfft) {
    int idx = blockIdx.x * 256 + threadIdx.x;     // grid covers 1536*512 + 512*512 = 1048576 exactly
    if (idx < NQKV * Cdim) {
        int n = idx >> 9, c = idx & 511;
        int proj = n >> 9, nn = n & 511;
        int h = nn >> 6, d = nn & 63;
        const float* w = (proj == 0) ? wq : (proj == 1 ? wk : wv);
        wqkvt[idx] = f2b(w[(h * Cdim + c) * Dh + d]);
    } else {
        int i2 = idx - NQKV * Cdim;
        int n = i2 >> 9, c = i2 & 511;
        wfft[i2] = f2b(wff[c * Cdim + n]);
    }
}

// ---------------- LayerNorm: fp32 in, bf16 out ----------------
__global__ __launch_bounds__(256) void k_ln(const float* __restrict__ x, const float* __restrict__ g,
                                            const float* __restrict__ b, short* __restrict__ out) {
    int row  = blockIdx.x * 4 + (threadIdx.x >> 6);   // one wave per token row
    int lane = threadIdx.x & 63;
    const f32x4 a0 = *(const f32x4*)(x + row * Cdim + lane * 8);
    const f32x4 a1 = *(const f32x4*)(x + row * Cdim + lane * 8 + 4);
    float v[8] = {a0[0], a0[1], a0[2], a0[3], a1[0], a1[1], a1[2], a1[3]};
    float s = 0.f, sq = 0.f;
#pragma unroll
    for (int i = 0; i < 8; i++) { s += v[i]; sq += v[i] * v[i]; }
#pragma unroll
    for (int off = 1; off < 64; off <<= 1) { s += __shfl_xor(s, off); sq += __shfl_xor(sq, off); }
    float mean = s * (1.f / 512.f);
    float var  = sq * (1.f / 512.f) - mean * mean;
    float rstd = rsqrtf(var + 1e-5f);
    const f32x4 g0 = *(const f32x4*)(g + lane * 8);
    const f32x4 g1 = *(const f32x4*)(g + lane * 8 + 4);
    const f32x4 b0 = *(const f32x4*)(b + lane * 8);
    const f32x4 b1 = *(const f32x4*)(b + lane * 8 + 4);
    float gg[8] = {g0[0], g0[1], g0[2], g0[3], g1[0], g1[1], g1[2], g1[3]};
    float bb[8] = {b0[0], b0[1], b0[2], b0[3], b1[0], b1[1], b1[2], b1[3]};
    bf16x8 o;
#pragma unroll
    for (int i = 0; i < 8; i++) o[i] = f2b((v[i] - mean) * rstd * gg[i] + bb[i]);
    *(bf16x8*)(out + row * Cdim + lane * 8) = o;
}

// ---------------- QKV GEMM: [8192,512] x Wt[1536,512], all bf16 ----------------
// 32x64 wave tiles (was 64x64): 2x the waves (24/CU) to hide global-load latency.
__global__ __launch_bounds__(256) void k_gemm_qkv(const short* __restrict__ A, const short* __restrict__ Wt,
                                                  short* __restrict__ q, short* __restrict__ k,
                                                  short* __restrict__ vt) {
    const int wave = threadIdx.x >> 6, lane = threadIdx.x & 63;
    const int quad = lane >> 4, l15 = lane & 15;
    const int m0 = blockIdx.x * 128 + wave * 32;
    const int n0 = blockIdx.y * 64;
    f32x4 acc[2][4];
#pragma unroll
    for (int i = 0; i < 2; i++)
#pragma unroll
        for (int j = 0; j < 4; j++) acc[i][j] = (f32x4){0.f, 0.f, 0.f, 0.f};
    const short* Ab = A  + (m0 + l15) * Cdim + quad * 8;
    const short* Bb = Wt + (n0 + l15) * Cdim + quad * 8;
#pragma unroll 4
    for (int ks = 0; ks < 16; ks++) {
        bf16x8 a[2], w[4];
#pragma unroll
        for (int mt = 0; mt < 2; mt++) a[mt] = *(const bf16x8*)(Ab + mt * 16 * Cdim + ks * 32);
#pragma unroll
        for (int nt = 0; nt < 4; nt++) w[nt] = *(const bf16x8*)(Bb + nt * 16 * Cdim + ks * 32);
#pragma unroll
        for (int mt = 0; mt < 2; mt++)
#pragma unroll
            for (int nt = 0; nt < 4; nt++)
                acc[mt][nt] = __builtin_amdgcn_mfma_f32_16x16x32_bf16(a[mt], w[nt], acc[mt][nt], 0, 0, 0);
    }
    // epilogue: whole block lies in one projection + one head (n-tile = 64 = head size)
    const int proj = n0 >> 9;
    const int hh   = (n0 & 511) >> 6;
#pragma unroll
    for (int mt = 0; mt < 2; mt++) {
#pragma unroll
        for (int r = 0; r < 4; r++) {
            int t  = m0 + mt * 16 + quad * 4 + r;
            int bi = t >> 11, tt = t & 2047;
#pragma unroll
            for (int nt = 0; nt < 4; nt++) {
                int d = nt * 16 + l15;
                short val = f2b(acc[mt][nt][r]);
                if (proj == 0)      q [((bi * Hn + hh) * Tseq + tt) * Dh + d] = val;
                else if (proj == 1) k [((bi * Hn + hh) * Tseq + tt) * Dh + d] = val;
                else                vt[((bi * Hn + hh) * Dh + d) * Tseq + tt] = val;
            }
        }
    }
}

// ---------------- causal flash attention, v6 (round-8 proven best: 173us) ----------------
__global__ __launch_bounds__(256) void k_attn(const short* __restrict__ qb, const short* __restrict__ kb,
                                              const short* __restrict__ vtb, const float* __restrict__ x,
                                              float* __restrict__ out1) {
    const int wave = threadIdx.x >> 6, lane = threadIdx.x & 63;
    const int quad = lane >> 4, l15 = lane & 15;
    const int bh = blockIdx.y;
    const int qtile = 127 - blockIdx.x;         // heavy-first (LPT)
    const int q0 = qtile * 16;
    const short* Q = qb  + bh * Tseq * Dh;
    const short* K = kb  + bh * Tseq * Dh;
    const short* V = vtb + bh * Dh * Tseq;      // [d][s]

    __shared__ __align__(16) float ldsO[4][16][64];   // combine zones; P tiles overlay in-loop
    __shared__ float ldsM[4][16];
    __shared__ float ldsL[4][16];
    short* pw = (short*)&ldsO[0][0][0] + wave * (16 * 72);  // 16x64 P tile, stride 72

    bf16x8 qa[2];
#pragma unroll
    for (int c = 0; c < 2; c++)
        qa[c] = *(const bf16x8*)(Q + (q0 + l15) * Dh + c * 32 + quad * 8);

    f32x4 o[4];
#pragma unroll
    for (int i = 0; i < 4; i++) o[i] = (f32x4){0.f, 0.f, 0.f, 0.f};
    float m_i = NEG_BIG, l_i = 0.f;             // per-lane: this lane's q = q0 + l15

    const float sc = 0.125f * 1.44269504089f;   // scale * log2(e): softmax in exp2 domain
    const int nkt = (q0 + 79) >> 6;             // 64-key tiles covering keys <= q0+15
    for (int kt = wave; kt < nkt; kt += 4) {    // strided split-K across the 4 waves
        const int s0 = kt * 64;
        f32x4 st[4];
#pragma unroll
        for (int nt = 0; nt < 4; nt++) {
            bf16x8 k0 = *(const bf16x8*)(K + (s0 + nt * 16 + l15) * Dh + quad * 8);
            bf16x8 k1 = *(const bf16x8*)(K + (s0 + nt * 16 + l15) * Dh + 32 + quad * 8);
            f32x4 z = (f32x4){0.f, 0.f, 0.f, 0.f};
            z = __builtin_amdgcn_mfma_f32_16x16x32_bf16(k0, qa[0], z, 0, 0, 0);
            z = __builtin_amdgcn_mfma_f32_16x16x32_bf16(k1, qa[1], z, 0, 0, 0);
            st[nt] = z;
        }
        const int qq = q0 + l15;
        if (s0 + 63 > q0) {                     // wave-uniform: only causal-boundary tiles mask
#pragma unroll
            for (int nt = 0; nt < 4; nt++)
#pragma unroll
                for (int r = 0; r < 4; r++) {
                    int s = s0 + nt * 16 + quad * 4 + r;
                    st[nt][r] = (s > qq) ? NEG_BIG : st[nt][r] * sc;
                }
        } else {
#pragma unroll
            for (int nt = 0; nt < 4; nt++)
#pragma unroll
                for (int r = 0; r < 4; r++) st[nt][r] *= sc;
        }
        float mx = fmaxf(fmaxf(fmaxf(st[0][0], st[0][1]), fmaxf(st[0][2], st[0][3])),
                         fmaxf(fmaxf(st[1][0], st[1][1]), fmaxf(st[1][2], st[1][3])));
        mx = fmaxf(mx, fmaxf(fmaxf(fmaxf(st[2][0], st[2][1]), fmaxf(st[2][2], st[2][3])),
                             fmaxf(fmaxf(st[3][0], st[3][1]), fmaxf(st[3][2], st[3][3]))));
        mx = fmaxf(mx, __shfl_xor(mx, 16));
        mx = fmaxf(mx, __shfl_xor(mx, 32));
        float mn    = fmaxf(m_i, mx);
        float alpha = __builtin_amdgcn_exp2f(m_i - mn);
        m_i = mn;
        float rs = 0.f;
        bf16x4 pk[4];                           // P^T packed: r=0..3 contiguous per (nt)
#pragma unroll
        for (int nt = 0; nt < 4; nt++) {
#pragma unroll
            for (int r = 0; r < 4; r++) {
                float p = __builtin_amdgcn_exp2f(st[nt][r] - mn);   // masked -> 0
                rs += p;
                pk[nt][r] = f2b(p);
            }
        }
        rs += __shfl_xor(rs, 16);
        rs += __shfl_xor(rs, 32);
        l_i = l_i * alpha + rs;
        // P^T -> LDS: value (s=nt*16+quad*4+r, q=l15) at pw[q*72 + s]; 4x ds_write_b64
#pragma unroll
        for (int nt = 0; nt < 4; nt++)
            *(bf16x4*)(pw + l15 * 72 + nt * 16 + quad * 4) = pk[nt];
        // rescale O: alpha lives at lane l15=q; O rows are q=quad*4+r
#pragma unroll
        for (int r = 0; r < 4; r++) {
            float ar = __shfl(alpha, quad * 4 + r);
#pragma unroll
            for (int dt = 0; dt < 4; dt++) o[dt][r] *= ar;
        }
        asm volatile("s_waitcnt lgkmcnt(0)" ::: "memory");
        bf16x8 pa[2];
#pragma unroll
        for (int c = 0; c < 2; c++)
            pa[c] = *(const bf16x8*)(pw + l15 * 72 + c * 32 + quad * 8);
#pragma unroll
        for (int c = 0; c < 2; c++)
#pragma unroll
            for (int v4 = 0; v4 < 4; v4++) {
                bf16x8 vb = *(const bf16x8*)(V + (v4 * 16 + l15) * Tseq + s0 + c * 32 + quad * 8);
                o[v4] = __builtin_amdgcn_mfma_f32_16x16x32_bf16(pa[c], vb, o[v4], 0, 0, 0);
            }
    }
    // ---- flash-combine of the 4 wave partials (m,l per-lane at q=l15) ----
    if (quad == 0) ldsM[wave][l15] = m_i;
    __syncthreads();                            // all loops done; P-scratch dead from here
    float Ml = fmaxf(fmaxf(ldsM[0][l15], ldsM[1][l15]), fmaxf(ldsM[2][l15], ldsM[3][l15]));
    float swl = __builtin_amdgcn_exp2f(m_i - Ml);            // empty wave: exp2(-1e30-M)=0
    l_i *= swl;
    if (quad == 0) ldsL[wave][l15] = l_i;
#pragma unroll
    for (int r = 0; r < 4; r++) {
        int row = quad * 4 + r;
        float Mr  = fmaxf(fmaxf(ldsM[0][row], ldsM[1][row]), fmaxf(ldsM[2][row], ldsM[3][row]));
        float swr = __builtin_amdgcn_exp2f(ldsM[wave][row] - Mr);
#pragma unroll
        for (int v4 = 0; v4 < 4; v4++)
            ldsO[wave][row][v4 * 16 + l15] = o[v4][r] * swr;
    }
    __syncthreads();
    // wave w sums rows 4w..4w+3; lane covers col = lane (coalesced 256B stores)
    const int bi = bh >> 3, hh = bh & 7;
#pragma unroll
    for (int j = 0; j < 4; j++) {
        int row = wave * 4 + j;
        float L  = ldsL[0][row] + ldsL[1][row] + ldsL[2][row] + ldsL[3][row];
        float Of = ldsO[0][row][lane] + ldsO[1][row][lane] + ldsO[2][row][lane] + ldsO[3][row][lane];
        int t   = q0 + row;
        int idx = (bi * Tseq + t) * Cdim + hh * Dh + lane;
        out1[idx] = x[idx] + Of / L;
    }
}

// ---------------- FF GEMM: [8192,512] x Wt[512,512], fused bias+ReLU+residual, fp32 out ----------------
// 32x64 wave tiles: grid (64,8) = 512 blocks -> 8 waves/CU (was 4: 1 block/CU!).
__global__ __launch_bounds__(256) void k_gemm_ff(const short* __restrict__ A, const short* __restrict__ Wt,
                                                 const float* __restrict__ bias, const float* __restrict__ res,
                                                 float* __restrict__ out) {
    const int wave = threadIdx.x >> 6, lane = threadIdx.x & 63;
    const int quad = lane >> 4, l15 = lane & 15;
    const int m0 = blockIdx.x * 128 + wave * 32;
    const int n0 = blockIdx.y * 64;
    f32x4 acc[2][4];
#pragma unroll
    for (int i = 0; i < 2; i++)
#pragma unroll
        for (int j = 0; j < 4; j++) acc[i][j] = (f32x4){0.f, 0.f, 0.f, 0.f};
    const short* Ab = A  + (m0 + l15) * Cdim + quad * 8;
    const short* Bb = Wt + (n0 + l15) * Cdim + quad * 8;
#pragma unroll 4
    for (int ks = 0; ks < 16; ks++) {
        bf16x8 a[2], w[4];
#pragma unroll
        for (int mt = 0; mt < 2; mt++) a[mt] = *(const bf16x8*)(Ab + mt * 16 * Cdim + ks * 32);
#pragma unroll
        for (int nt = 0; nt < 4; nt++) w[nt] = *(const bf16x8*)(Bb + nt * 16 * Cdim + ks * 32);
#pragma unroll
        for (int mt = 0; mt < 2; mt++)
#pragma unroll
            for (int nt = 0; nt < 4; nt++)
                acc[mt][nt] = __builtin_amdgcn_mfma_f32_16x16x32_bf16(a[mt], w[nt], acc[mt][nt], 0, 0, 0);
    }
#pragma unroll
    for (int mt = 0; mt < 2; mt++) {
#pragma unroll
        for (int r = 0; r < 4; r++) {
            int t = m0 + mt * 16 + quad * 4 + r;
#pragma unroll
            for (int nt = 0; nt < 4; nt++) {
                int n = n0 + nt * 16 + l15;
                float fv = acc[mt][nt][r] + bias[n];
                fv = fmaxf(fv, 0.f);
                out[t * Cdim + n] = res[t * Cdim + n] + fv;
            }
        }
    }
}

extern "C" void kernel_launch(void* const* d_in, const int* in_sizes, int n_in,
                              void* d_out, int out_size, void* d_ws, size_t ws_size,
                              hipStream_t stream) {
    const float* x   = (const float*)d_in[0];
    const float* wq  = (const float*)d_in[1];
    const float* wk  = (const float*)d_in[2];
    const float* wv  = (const float*)d_in[3];
    const float* wff = (const float*)d_in[4];
    const float* bff = (const float*)d_in[5];
    const float* g1  = (const float*)d_in[6];
    const float* b1  = (const float*)d_in[7];
    const float* g2  = (const float*)d_in[8];
    const float* b2  = (const float*)d_in[9];

    char* p = (char*)d_ws;                                  // ~50 MB total scratch
    short* wqkvt = (short*)p; p += (size_t)NQKV * Cdim * 2;
    short* wfft  = (short*)p; p += (size_t)Cdim * Cdim * 2;
    short* h1    = (short*)p; p += (size_t)BT * Cdim * 2;   // reused as h2 after attention
    short* qb    = (short*)p; p += (size_t)BT * Cdim * 2;
    short* kb    = (short*)p; p += (size_t)BT * Cdim * 2;
    short* vtb   = (short*)p; p += (size_t)BT * Cdim * 2;
    float* out1  = (float*)p; p += (size_t)BT * Cdim * 4;

    hipLaunchKernelGGL(k_transpose, dim3(4096),    dim3(256), 0, stream, wq, wk, wv, wff, wqkvt, wfft);
    hipLaunchKernelGGL(k_ln,        dim3(2048),    dim3(256), 0, stream, x, g1, b1, h1);
    hipLaunchKernelGGL(k_gemm_qkv,  dim3(64, 24),  dim3(256), 0, stream, h1, wqkvt, qb, kb, vtb);
    hipLaunchKernelGGL(k_attn,      dim3(128, 32), dim3(256), 0, stream, qb, kb, vtb, x, out1);
    hipLaunchKernelGGL(k_ln,        dim3(2048),    dim3(256), 0, stream, out1, g2, b2, h1);
    hipLaunchKernelGGL(k_gemm_ff,   dim3(64, 8),   dim3(256), 0, stream, h1, wfft, bff, out1, (float*)d_out);
}

// Round 11
// 321.293 us; speedup vs baseline: 1.2761x; 1.1091x over previous
//
#include <hip/hip_runtime.h>

#define Bsz  4
#define Tseq 2048
#define Cdim 512
#define Hn   8
#define Dh   64
#define BT   8192     // Bsz*Tseq tokens
#define NQKV 1536
#define NEG_BIG (-1e30f)

typedef __attribute__((ext_vector_type(8))) short bf16x8;  // 8 bf16 = 4 VGPRs
typedef __attribute__((ext_vector_type(4))) short bf16x4;  // 4 bf16 = 2 VGPRs
typedef __attribute__((ext_vector_type(4))) float f32x4;

__device__ __forceinline__ float b2f(short s) {
    unsigned u = ((unsigned)(unsigned short)s) << 16;
    float f; __builtin_memcpy(&f, &u, 4); return f;
}
__device__ __forceinline__ short f2b(float f) {
    unsigned u; __builtin_memcpy(&u, &f, 4);
    u = (u + 0x7fffu + ((u >> 16) & 1u)) >> 16;   // RNE
    return (short)u;
}

// ---------------- weight transpose + bf16 cast: W[c][n] (fp32) -> Wt[n][c] (bf16) ----------------
__global__ __launch_bounds__(256) void k_transpose(const float* __restrict__ wq, const float* __restrict__ wk,
                                                   const float* __restrict__ wv, const float* __restrict__ wff,
                                                   short* __restrict__ wqkvt, short* __restrict__ wfft) {
    int idx = blockIdx.x * 256 + threadIdx.x;     // grid covers 1536*512 + 512*512 = 1048576 exactly
    if (idx < NQKV * Cdim) {
        int n = idx >> 9, c = idx & 511;
        int proj = n >> 9, nn = n & 511;
        int h = nn >> 6, d = nn & 63;
        const float* w = (proj == 0) ? wq : (proj == 1 ? wk : wv);
        wqkvt[idx] = f2b(w[(h * Cdim + c) * Dh + d]);
    } else {
        int i2 = idx - NQKV * Cdim;
        int n = i2 >> 9, c = i2 & 511;
        wfft[i2] = f2b(wff[c * Cdim + n]);
    }
}

// ---------------- LayerNorm: fp32 in, bf16 out ----------------
__global__ __launch_bounds__(256) void k_ln(const float* __restrict__ x, const float* __restrict__ g,
                                            const float* __restrict__ b, short* __restrict__ out) {
    int row  = blockIdx.x * 4 + (threadIdx.x >> 6);   // one wave per token row
    int lane = threadIdx.x & 63;
    const f32x4 a0 = *(const f32x4*)(x + row * Cdim + lane * 8);
    const f32x4 a1 = *(const f32x4*)(x + row * Cdim + lane * 8 + 4);
    float v[8] = {a0[0], a0[1], a0[2], a0[3], a1[0], a1[1], a1[2], a1[3]};
    float s = 0.f, sq = 0.f;
#pragma unroll
    for (int i = 0; i < 8; i++) { s += v[i]; sq += v[i] * v[i]; }
#pragma unroll
    for (int off = 1; off < 64; off <<= 1) { s += __shfl_xor(s, off); sq += __shfl_xor(sq, off); }
    float mean = s * (1.f / 512.f);
    float var  = sq * (1.f / 512.f) - mean * mean;
    float rstd = rsqrtf(var + 1e-5f);
    const f32x4 g0 = *(const f32x4*)(g + lane * 8);
    const f32x4 g1 = *(const f32x4*)(g + lane * 8 + 4);
    const f32x4 b0 = *(const f32x4*)(b + lane * 8);
    const f32x4 b1 = *(const f32x4*)(b + lane * 8 + 4);
    float gg[8] = {g0[0], g0[1], g0[2], g0[3], g1[0], g1[1], g1[2], g1[3]};
    float bb[8] = {b0[0], b0[1], b0[2], b0[3], b1[0], b1[1], b1[2], b1[3]};
    bf16x8 o;
#pragma unroll
    for (int i = 0; i < 8; i++) o[i] = f2b((v[i] - mean) * rstd * gg[i] + bb[i]);
    *(bf16x8*)(out + row * Cdim + lane * 8) = o;
}

// ---------------- QKV GEMM: [8192,512] x Wt[1536,512], all bf16 (round-8 64x64 tiles) ----------------
__global__ __launch_bounds__(256) void k_gemm_qkv(const short* __restrict__ A, const short* __restrict__ Wt,
                                                  short* __restrict__ q, short* __restrict__ k,
                                                  short* __restrict__ vt) {
    const int wave = threadIdx.x >> 6, lane = threadIdx.x & 63;
    const int quad = lane >> 4, l15 = lane & 15;
    const int m0 = blockIdx.x * 256 + wave * 64;
    const int n0 = blockIdx.y * 64;
    f32x4 acc[4][4];
#pragma unroll
    for (int i = 0; i < 4; i++)
#pragma unroll
        for (int j = 0; j < 4; j++) acc[i][j] = (f32x4){0.f, 0.f, 0.f, 0.f};
    const short* Ab = A  + (m0 + l15) * Cdim + quad * 8;
    const short* Bb = Wt + (n0 + l15) * Cdim + quad * 8;
#pragma unroll 2
    for (int ks = 0; ks < 16; ks++) {
        bf16x8 a[4], w[4];
#pragma unroll
        for (int mt = 0; mt < 4; mt++) a[mt] = *(const bf16x8*)(Ab + mt * 16 * Cdim + ks * 32);
#pragma unroll
        for (int nt = 0; nt < 4; nt++) w[nt] = *(const bf16x8*)(Bb + nt * 16 * Cdim + ks * 32);
#pragma unroll
        for (int mt = 0; mt < 4; mt++)
#pragma unroll
            for (int nt = 0; nt < 4; nt++)
                acc[mt][nt] = __builtin_amdgcn_mfma_f32_16x16x32_bf16(a[mt], w[nt], acc[mt][nt], 0, 0, 0);
    }
    // epilogue: whole block lies in one projection + one head (n-tile = 64 = head size)
    const int proj = n0 >> 9;
    const int hh   = (n0 & 511) >> 6;
#pragma unroll
    for (int mt = 0; mt < 4; mt++) {
#pragma unroll
        for (int r = 0; r < 4; r++) {
            int t  = m0 + mt * 16 + quad * 4 + r;
            int bi = t >> 11, tt = t & 2047;
#pragma unroll
            for (int nt = 0; nt < 4; nt++) {
                int d = nt * 16 + l15;
                short val = f2b(acc[mt][nt][r]);
                if (proj == 0)      q [((bi * Hn + hh) * Tseq + tt) * Dh + d] = val;
                else if (proj == 1) k [((bi * Hn + hh) * Tseq + tt) * Dh + d] = val;
                else                vt[((bi * Hn + hh) * Dh + d) * Tseq + tt] = val;
            }
        }
    }
}

// ---------------- causal flash attention, v8: v6 + CU-balance swizzle ----------------
// Work/block ~ qtile, and CU assignment samples linear block ids at stride ~256 = 2*gridDim.x,
// so qtile = f(blockIdx.x) alone gives every CU the SAME qtile 16x (2x max/mean skew).
// Diagonal swizzle qtile = (x + y) & 127 makes each CU sweep qtiles across the range.
__global__ __launch_bounds__(256) void k_attn(const short* __restrict__ qb, const short* __restrict__ kb,
                                              const short* __restrict__ vtb, const float* __restrict__ x,
                                              float* __restrict__ out1) {
    const int wave = threadIdx.x >> 6, lane = threadIdx.x & 63;
    const int quad = lane >> 4, l15 = lane & 15;
    const int bh = blockIdx.y;
    const int qtile = (blockIdx.x + blockIdx.y) & 127;   // CU-balance swizzle
    const int q0 = qtile * 16;
    const short* Q = qb  + bh * Tseq * Dh;
    const short* K = kb  + bh * Tseq * Dh;
    const short* V = vtb + bh * Dh * Tseq;      // [d][s]

    __shared__ __align__(16) float ldsO[4][16][64];   // combine zones; P tiles overlay in-loop
    __shared__ float ldsM[4][16];
    __shared__ float ldsL[4][16];
    short* pw = (short*)&ldsO[0][0][0] + wave * (16 * 72);  // 16x64 P tile, stride 72

    bf16x8 qa[2];
#pragma unroll
    for (int c = 0; c < 2; c++)
        qa[c] = *(const bf16x8*)(Q + (q0 + l15) * Dh + c * 32 + quad * 8);

    f32x4 o[4];
#pragma unroll
    for (int i = 0; i < 4; i++) o[i] = (f32x4){0.f, 0.f, 0.f, 0.f};
    float m_i = NEG_BIG, l_i = 0.f;             // per-lane: this lane's q = q0 + l15

    const float sc = 0.125f * 1.44269504089f;   // scale * log2(e): softmax in exp2 domain
    const int nkt = (q0 + 79) >> 6;             // 64-key tiles covering keys <= q0+15
    for (int kt = wave; kt < nkt; kt += 4) {    // strided split-K across the 4 waves
        const int s0 = kt * 64;
        f32x4 st[4];
#pragma unroll
        for (int nt = 0; nt < 4; nt++) {
            bf16x8 k0 = *(const bf16x8*)(K + (s0 + nt * 16 + l15) * Dh + quad * 8);
            bf16x8 k1 = *(const bf16x8*)(K + (s0 + nt * 16 + l15) * Dh + 32 + quad * 8);
            f32x4 z = (f32x4){0.f, 0.f, 0.f, 0.f};
            z = __builtin_amdgcn_mfma_f32_16x16x32_bf16(k0, qa[0], z, 0, 0, 0);
            z = __builtin_amdgcn_mfma_f32_16x16x32_bf16(k1, qa[1], z, 0, 0, 0);
            st[nt] = z;
        }
        const int qq = q0 + l15;
        if (s0 + 63 > q0) {                     // wave-uniform: only causal-boundary tiles mask
#pragma unroll
            for (int nt = 0; nt < 4; nt++)
#pragma unroll
                for (int r = 0; r < 4; r++) {
                    int s = s0 + nt * 16 + quad * 4 + r;
                    st[nt][r] = (s > qq) ? NEG_BIG : st[nt][r] * sc;
                }
        } else {
#pragma unroll
            for (int nt = 0; nt < 4; nt++)
#pragma unroll
                for (int r = 0; r < 4; r++) st[nt][r] *= sc;
        }
        float mx = fmaxf(fmaxf(fmaxf(st[0][0], st[0][1]), fmaxf(st[0][2], st[0][3])),
                         fmaxf(fmaxf(st[1][0], st[1][1]), fmaxf(st[1][2], st[1][3])));
        mx = fmaxf(mx, fmaxf(fmaxf(fmaxf(st[2][0], st[2][1]), fmaxf(st[2][2], st[2][3])),
                             fmaxf(fmaxf(st[3][0], st[3][1]), fmaxf(st[3][2], st[3][3]))));
        mx = fmaxf(mx, __shfl_xor(mx, 16));
        mx = fmaxf(mx, __shfl_xor(mx, 32));
        float mn    = fmaxf(m_i, mx);
        float alpha = __builtin_amdgcn_exp2f(m_i - mn);
        m_i = mn;
        float rs = 0.f;
        bf16x4 pk[4];                           // P^T packed: r=0..3 contiguous per (nt)
#pragma unroll
        for (int nt = 0; nt < 4; nt++) {
#pragma unroll
            for (int r = 0; r < 4; r++) {
                float p = __builtin_amdgcn_exp2f(st[nt][r] - mn);   // masked -> 0
                rs += p;
                pk[nt][r] = f2b(p);
            }
        }
        rs += __shfl_xor(rs, 16);
        rs += __shfl_xor(rs, 32);
        l_i = l_i * alpha + rs;
        // P^T -> LDS: value (s=nt*16+quad*4+r, q=l15) at pw[q*72 + s]; 4x ds_write_b64
#pragma unroll
        for (int nt = 0; nt < 4; nt++)
            *(bf16x4*)(pw + l15 * 72 + nt * 16 + quad * 4) = pk[nt];
        // rescale O: alpha lives at lane l15=q; O rows are q=quad*4+r
#pragma unroll
        for (int r = 0; r < 4; r++) {
            float ar = __shfl(alpha, quad * 4 + r);
#pragma unroll
            for (int dt = 0; dt < 4; dt++) o[dt][r] *= ar;
        }
        asm volatile("s_waitcnt lgkmcnt(0)" ::: "memory");
        bf16x8 pa[2];
#pragma unroll
        for (int c = 0; c < 2; c++)
            pa[c] = *(const bf16x8*)(pw + l15 * 72 + c * 32 + quad * 8);
#pragma unroll
        for (int c = 0; c < 2; c++)
#pragma unroll
            for (int v4 = 0; v4 < 4; v4++) {
                bf16x8 vb = *(const bf16x8*)(V + (v4 * 16 + l15) * Tseq + s0 + c * 32 + quad * 8);
                o[v4] = __builtin_amdgcn_mfma_f32_16x16x32_bf16(pa[c], vb, o[v4], 0, 0, 0);
            }
    }
    // ---- flash-combine of the 4 wave partials (m,l per-lane at q=l15) ----
    if (quad == 0) ldsM[wave][l15] = m_i;
    __syncthreads();                            // all loops done; P-scratch dead from here
    float Ml = fmaxf(fmaxf(ldsM[0][l15], ldsM[1][l15]), fmaxf(ldsM[2][l15], ldsM[3][l15]));
    float swl = __builtin_amdgcn_exp2f(m_i - Ml);            // empty wave: exp2(-1e30-M)=0
    l_i *= swl;
    if (quad == 0) ldsL[wave][l15] = l_i;
#pragma unroll
    for (int r = 0; r < 4; r++) {
        int row = quad * 4 + r;
        float Mr  = fmaxf(fmaxf(ldsM[0][row], ldsM[1][row]), fmaxf(ldsM[2][row], ldsM[3][row]));
        float swr = __builtin_amdgcn_exp2f(ldsM[wave][row] - Mr);
#pragma unroll
        for (int v4 = 0; v4 < 4; v4++)
            ldsO[wave][row][v4 * 16 + l15] = o[v4][r] * swr;
    }
    __syncthreads();
    // wave w sums rows 4w..4w+3; lane covers col = lane (coalesced 256B stores)
    const int bi = bh >> 3, hh = bh & 7;
#pragma unroll
    for (int j = 0; j < 4; j++) {
        int row = wave * 4 + j;
        float L  = ldsL[0][row] + ldsL[1][row] + ldsL[2][row] + ldsL[3][row];
        float Of = ldsO[0][row][lane] + ldsO[1][row][lane] + ldsO[2][row][lane] + ldsO[3][row][lane];
        int t   = q0 + row;
        int idx = (bi * Tseq + t) * Cdim + hh * Dh + lane;
        out1[idx] = x[idx] + Of / L;
    }
}

// ---------------- FF GEMM: [8192,512] x Wt[512,512], fused bias+ReLU+residual, fp32 out ----------------
__global__ __launch_bounds__(256) void k_gemm_ff(const short* __restrict__ A, const short* __restrict__ Wt,
                                                 const float* __restrict__ bias, const float* __restrict__ res,
                                                 float* __restrict__ out) {
    const int wave = threadIdx.x >> 6, lane = threadIdx.x & 63;
    const int quad = lane >> 4, l15 = lane & 15;
    const int m0 = blockIdx.x * 256 + wave * 64;
    const int n0 = blockIdx.y * 64;
    f32x4 acc[4][4];
#pragma unroll
    for (int i = 0; i < 4; i++)
#pragma unroll
        for (int j = 0; j < 4; j++) acc[i][j] = (f32x4){0.f, 0.f, 0.f, 0.f};
    const short* Ab = A  + (m0 + l15) * Cdim + quad * 8;
    const short* Bb = Wt + (n0 + l15) * Cdim + quad * 8;
#pragma unroll 2
    for (int ks = 0; ks < 16; ks++) {
        bf16x8 a[4], w[4];
#pragma unroll
        for (int mt = 0; mt < 4; mt++) a[mt] = *(const bf16x8*)(Ab + mt * 16 * Cdim + ks * 32);
#pragma unroll
        for (int nt = 0; nt < 4; nt++) w[nt] = *(const bf16x8*)(Bb + nt * 16 * Cdim + ks * 32);
#pragma unroll
        for (int mt = 0; mt < 4; mt++)
#pragma unroll
            for (int nt = 0; nt < 4; nt++)
                acc[mt][nt] = __builtin_amdgcn_mfma_f32_16x16x32_bf16(a[mt], w[nt], acc[mt][nt], 0, 0, 0);
    }
#pragma unroll
    for (int mt = 0; mt < 4; mt++) {
#pragma unroll
        for (int r = 0; r < 4; r++) {
            int t = m0 + mt * 16 + quad * 4 + r;
#pragma unroll
            for (int nt = 0; nt < 4; nt++) {
                int n = n0 + nt * 16 + l15;
                float fv = acc[mt][nt][r] + bias[n];
                fv = fmaxf(fv, 0.f);
                out[t * Cdim + n] = res[t * Cdim + n] + fv;
            }
        }
    }
}

extern "C" void kernel_launch(void* const* d_in, const int* in_sizes, int n_in,
                              void* d_out, int out_size, void* d_ws, size_t ws_size,
                              hipStream_t stream) {
    const float* x   = (const float*)d_in[0];
    const float* wq  = (const float*)d_in[1];
    const float* wk  = (const float*)d_in[2];
    const float* wv  = (const float*)d_in[3];
    const float* wff = (const float*)d_in[4];
    const float* bff = (const float*)d_in[5];
    const float* g1  = (const float*)d_in[6];
    const float* b1  = (const float*)d_in[7];
    const float* g2  = (const float*)d_in[8];
    const float* b2  = (const float*)d_in[9];

    char* p = (char*)d_ws;                                  // ~50 MB total scratch
    short* wqkvt = (short*)p; p += (size_t)NQKV * Cdim * 2;
    short* wfft  = (short*)p; p += (size_t)Cdim * Cdim * 2;
    short* h1    = (short*)p; p += (size_t)BT * Cdim * 2;   // reused as h2 after attention
    short* qb    = (short*)p; p += (size_t)BT * Cdim * 2;
    short* kb    = (short*)p; p += (size_t)BT * Cdim * 2;
    short* vtb   = (short*)p; p += (size_t)BT * Cdim * 2;
    float* out1  = (float*)p; p += (size_t)BT * Cdim * 4;

    hipLaunchKernelGGL(k_transpose, dim3(4096),    dim3(256), 0, stream, wq, wk, wv, wff, wqkvt, wfft);
    hipLaunchKernelGGL(k_ln,        dim3(2048),    dim3(256), 0, stream, x, g1, b1, h1);
    hipLaunchKernelGGL(k_gemm_qkv,  dim3(32, 24),  dim3(256), 0, stream, h1, wqkvt, qb, kb, vtb);
    hipLaunchKernelGGL(k_attn,      dim3(128, 32), dim3(256), 0, stream, qb, kb, vtb, x, out1);
    hipLaunchKernelGGL(k_ln,        dim3(2048),    dim3(256), 0, stream, out1, g2, b2, h1);
    hipLaunchKernelGGL(k_gemm_ff,   dim3(32, 8),   dim3(256), 0, stream, h1, wfft, bff, out1, (float*)d_out);
}

// Round 12
// 284.882 us; speedup vs baseline: 1.4392x; 1.1278x over previous
//
#include <hip/hip_runtime.h>

#define Bsz  4
#define Tseq 2048
#define Cdim 512
#define Hn   8
#define Dh   64
#define BT   8192     // Bsz*Tseq tokens
#define NQKV 1536
#define NEG_BIG (-1e30f)

typedef __attribute__((ext_vector_type(8))) short bf16x8;  // 8 bf16 = 4 VGPRs
typedef __attribute__((ext_vector_type(4))) short bf16x4;  // 4 bf16 = 2 VGPRs
typedef __attribute__((ext_vector_type(4))) float f32x4;

__device__ __forceinline__ float b2f(short s) {
    unsigned u = ((unsigned)(unsigned short)s) << 16;
    float f; __builtin_memcpy(&f, &u, 4); return f;
}
__device__ __forceinline__ short f2b(float f) {
    unsigned u; __builtin_memcpy(&u, &f, 4);
    u = (u + 0x7fffu + ((u >> 16) & 1u)) >> 16;   // RNE
    return (short)u;
}
// async global->LDS, 16B/lane; LDS dest = wave-uniform base + lane*16
__device__ __forceinline__ void g2l16(const short* g, short* l) {
    __builtin_amdgcn_global_load_lds(
        (const __attribute__((address_space(1))) unsigned int*)(uintptr_t)g,
        (__attribute__((address_space(3))) unsigned int*)l, 16, 0, 0);
}

// ---------------- prep: fused weight transpose (blocks 0..255) + LayerNorm1 (blocks 256..2303) ----------------
__global__ __launch_bounds__(256) void k_prep(const float* __restrict__ wq, const float* __restrict__ wk,
                                              const float* __restrict__ wv, const float* __restrict__ wff,
                                              short* __restrict__ wqkvt, short* __restrict__ wfft,
                                              const float* __restrict__ x, const float* __restrict__ g,
                                              const float* __restrict__ b, short* __restrict__ out) {
    const int blk = blockIdx.x, tid = threadIdx.x;
    if (blk < 256) {
        __shared__ float ldsT[64 * 65];          // 64x64 tile, pad 65: conflict-free both phases
        if (blk < 192) {                         // QKV heads: per-head 512x64 -> 64x512
            int hm = blk >> 3, ct = blk & 7;
            int proj = hm >> 3, h = hm & 7;
            const float* w = (proj == 0) ? wq : (proj == 1 ? wk : wv);
#pragma unroll
            for (int i = 0; i < 16; i++) {
                int flat = i * 256 + tid, cc = flat >> 6, dd = flat & 63;
                ldsT[dd * 65 + cc] = w[(h * 512 + ct * 64 + cc) * 64 + dd];   // coalesced in dd
            }
            __syncthreads();
#pragma unroll
            for (int i = 0; i < 16; i++) {
                int flat = i * 256 + tid, dd = flat >> 6, cc = flat & 63;
                int n = proj * 512 + h * 64 + dd;
                wqkvt[n * 512 + ct * 64 + cc] = f2b(ldsT[dd * 65 + cc]);      // coalesced in cc
            }
        } else {                                 // FF: 512x512 -> 512x512 transposed
            int b2 = blk - 192, rt = b2 >> 3, nt8 = b2 & 7;
#pragma unroll
            for (int i = 0; i < 16; i++) {
                int flat = i * 256 + tid, cc = flat >> 6, nn = flat & 63;
                ldsT[nn * 65 + cc] = wff[(rt * 64 + cc) * 512 + nt8 * 64 + nn];
            }
            __syncthreads();
#pragma unroll
            for (int i = 0; i < 16; i++) {
                int flat = i * 256 + tid, nn = flat >> 6, cc = flat & 63;
                wfft[(nt8 * 64 + nn) * 512 + rt * 64 + cc] = f2b(ldsT[nn * 65 + cc]);
            }
        }
    } else {                                     // LayerNorm1: one wave per token row
        int row  = (blk - 256) * 4 + (tid >> 6);
        int lane = tid & 63;
        const f32x4 a0 = *(const f32x4*)(x + row * Cdim + lane * 8);
        const f32x4 a1 = *(const f32x4*)(x + row * Cdim + lane * 8 + 4);
        float v[8] = {a0[0], a0[1], a0[2], a0[3], a1[0], a1[1], a1[2], a1[3]};
        float s = 0.f, sq = 0.f;
#pragma unroll
        for (int i = 0; i < 8; i++) { s += v[i]; sq += v[i] * v[i]; }
#pragma unroll
        for (int off = 1; off < 64; off <<= 1) { s += __shfl_xor(s, off); sq += __shfl_xor(sq, off); }
        float mean = s * (1.f / 512.f);
        float var  = sq * (1.f / 512.f) - mean * mean;
        float rstd = rsqrtf(var + 1e-5f);
        const f32x4 g0 = *(const f32x4*)(g + lane * 8);
        const f32x4 g1 = *(const f32x4*)(g + lane * 8 + 4);
        const f32x4 b0 = *(const f32x4*)(b + lane * 8);
        const f32x4 b1 = *(const f32x4*)(b + lane * 8 + 4);
        float gg[8] = {g0[0], g0[1], g0[2], g0[3], g1[0], g1[1], g1[2], g1[3]};
        float bb[8] = {b0[0], b0[1], b0[2], b0[3], b1[0], b1[1], b1[2], b1[3]};
        bf16x8 o;
#pragma unroll
        for (int i = 0; i < 8; i++) o[i] = f2b((v[i] - mean) * rstd * gg[i] + bb[i]);
        *(bf16x8*)(out + row * Cdim + lane * 8) = o;
    }
}

// ---------------- LayerNorm (standalone, for LN2): fp32 in, bf16 out ----------------
__global__ __launch_bounds__(256) void k_ln(const float* __restrict__ x, const float* __restrict__ g,
                                            const float* __restrict__ b, short* __restrict__ out) {
    int row  = blockIdx.x * 4 + (threadIdx.x >> 6);
    int lane = threadIdx.x & 63;
    const f32x4 a0 = *(const f32x4*)(x + row * Cdim + lane * 8);
    const f32x4 a1 = *(const f32x4*)(x + row * Cdim + lane * 8 + 4);
    float v[8] = {a0[0], a0[1], a0[2], a0[3], a1[0], a1[1], a1[2], a1[3]};
    float s = 0.f, sq = 0.f;
#pragma unroll
    for (int i = 0; i < 8; i++) { s += v[i]; sq += v[i] * v[i]; }
#pragma unroll
    for (int off = 1; off < 64; off <<= 1) { s += __shfl_xor(s, off); sq += __shfl_xor(sq, off); }
    float mean = s * (1.f / 512.f);
    float var  = sq * (1.f / 512.f) - mean * mean;
    float rstd = rsqrtf(var + 1e-5f);
    const f32x4 g0 = *(const f32x4*)(g + lane * 8);
    const f32x4 g1 = *(const f32x4*)(g + lane * 8 + 4);
    const f32x4 b0 = *(const f32x4*)(b + lane * 8);
    const f32x4 b1 = *(const f32x4*)(b + lane * 8 + 4);
    float gg[8] = {g0[0], g0[1], g0[2], g0[3], g1[0], g1[1], g1[2], g1[3]};
    float bb[8] = {b0[0], b0[1], b0[2], b0[3], b1[0], b1[1], b1[2], b1[3]};
    bf16x8 o;
#pragma unroll
    for (int i = 0; i < 8; i++) o[i] = f2b((v[i] - mean) * rstd * gg[i] + bb[i]);
    *(bf16x8*)(out + row * Cdim + lane * 8) = o;
}

// ---------------- QKV GEMM v2: 128x128 block tile, LDS-staged via global_load_lds ----------------
// 2x2 waves of 64x64; BK=32; single-buffered (m97 2-barrier structure).
__global__ __launch_bounds__(256) void k_gemm_qkv(const short* __restrict__ A, const short* __restrict__ Wt,
                                                  short* __restrict__ q, short* __restrict__ k,
                                                  short* __restrict__ vt) {
    const int tid = threadIdx.x;
    const int wave = tid >> 6, lane = tid & 63;
    const int quad = lane >> 4, l15 = lane & 15;
    const int m0 = blockIdx.x * 128, n0 = blockIdx.y * 128;
    const int wm = wave & 1, wn = wave >> 1;
    __shared__ __align__(16) short As[128 * 32];   // [row][k] 64B rows
    __shared__ __align__(16) short Bs[128 * 32];
    f32x4 acc[4][4];
#pragma unroll
    for (int i = 0; i < 4; i++)
#pragma unroll
        for (int j = 0; j < 4; j++) acc[i][j] = (f32x4){0.f, 0.f, 0.f, 0.f};
    const int lr = lane >> 2, lc = lane & 3;       // staging: row = lane/4, 16B-col = lane%4
    const short* Ag = A  + (m0 + wave * 32 + lr) * Cdim + lc * 8;
    const short* Bg = Wt + (n0 + wave * 32 + lr) * Cdim + lc * 8;
    short* Al = As + wave * 1024;                  // wave-uniform LDS dest (shorts)
    short* Bl = Bs + wave * 1024;
    for (int kk = 0; kk < 16; kk++) {
        const int k0 = kk * 32;
        g2l16(Ag + k0,             Al);
        g2l16(Ag + 16 * Cdim + k0, Al + 512);
        g2l16(Bg + k0,             Bl);
        g2l16(Bg + 16 * Cdim + k0, Bl + 512);
        __syncthreads();                           // drains vmcnt before reads
        bf16x8 a[4], w[4];
#pragma unroll
        for (int mt = 0; mt < 4; mt++) a[mt] = *(const bf16x8*)(As + (wm * 64 + mt * 16 + l15) * 32 + quad * 8);
#pragma unroll
        for (int nt = 0; nt < 4; nt++) w[nt] = *(const bf16x8*)(Bs + (wn * 64 + nt * 16 + l15) * 32 + quad * 8);
#pragma unroll
        for (int mt = 0; mt < 4; mt++)
#pragma unroll
            for (int nt = 0; nt < 4; nt++)
                acc[mt][nt] = __builtin_amdgcn_mfma_f32_16x16x32_bf16(a[mt], w[nt], acc[mt][nt], 0, 0, 0);
        __syncthreads();                           // protect tiles before next staging
    }
    // epilogue: proj block-uniform (128 | 512), head wave-uniform (n0w 64-aligned)
    const int proj = n0 >> 9;
    const int n0w  = n0 + wn * 64;
    const int hh   = (n0w & 511) >> 6;
    const int m0w  = m0 + wm * 64;
#pragma unroll
    for (int mt = 0; mt < 4; mt++) {
#pragma unroll
        for (int r = 0; r < 4; r++) {
            int t  = m0w + mt * 16 + quad * 4 + r;
            int bi = t >> 11, tt = t & 2047;
#pragma unroll
            for (int nt = 0; nt < 4; nt++) {
                int d = nt * 16 + l15;
                short val = f2b(acc[mt][nt][r]);
                if (proj == 0)      q [((bi * Hn + hh) * Tseq + tt) * Dh + d] = val;
                else if (proj == 1) k [((bi * Hn + hh) * Tseq + tt) * Dh + d] = val;
                else                vt[((bi * Hn + hh) * Dh + d) * Tseq + tt] = val;
            }
        }
    }
}

// ---------------- causal flash attention, v8 (round-11 best: 158us) ----------------
__global__ __launch_bounds__(256) void k_attn(const short* __restrict__ qb, const short* __restrict__ kb,
                                              const short* __restrict__ vtb, const float* __restrict__ x,
                                              float* __restrict__ out1) {
    const int wave = threadIdx.x >> 6, lane = threadIdx.x & 63;
    const int quad = lane >> 4, l15 = lane & 15;
    const int bh = blockIdx.y;
    const int qtile = (blockIdx.x + blockIdx.y) & 127;   // CU-balance swizzle
    const int q0 = qtile * 16;
    const short* Q = qb  + bh * Tseq * Dh;
    const short* K = kb  + bh * Tseq * Dh;
    const short* V = vtb + bh * Dh * Tseq;      // [d][s]

    __shared__ __align__(16) float ldsO[4][16][64];   // combine zones; P tiles overlay in-loop
    __shared__ float ldsM[4][16];
    __shared__ float ldsL[4][16];
    short* pw = (short*)&ldsO[0][0][0] + wave * (16 * 72);  // 16x64 P tile, stride 72

    bf16x8 qa[2];
#pragma unroll
    for (int c = 0; c < 2; c++)
        qa[c] = *(const bf16x8*)(Q + (q0 + l15) * Dh + c * 32 + quad * 8);

    f32x4 o[4];
#pragma unroll
    for (int i = 0; i < 4; i++) o[i] = (f32x4){0.f, 0.f, 0.f, 0.f};
    float m_i = NEG_BIG, l_i = 0.f;             // per-lane: this lane's q = q0 + l15

    const float sc = 0.125f * 1.44269504089f;   // scale * log2(e): softmax in exp2 domain
    const int nkt = (q0 + 79) >> 6;             // 64-key tiles covering keys <= q0+15
    for (int kt = wave; kt < nkt; kt += 4) {    // strided split-K across the 4 waves
        const int s0 = kt * 64;
        f32x4 st[4];
#pragma unroll
        for (int nt = 0; nt < 4; nt++) {
            bf16x8 k0 = *(const bf16x8*)(K + (s0 + nt * 16 + l15) * Dh + quad * 8);
            bf16x8 k1 = *(const bf16x8*)(K + (s0 + nt * 16 + l15) * Dh + 32 + quad * 8);
            f32x4 z = (f32x4){0.f, 0.f, 0.f, 0.f};
            z = __builtin_amdgcn_mfma_f32_16x16x32_bf16(k0, qa[0], z, 0, 0, 0);
            z = __builtin_amdgcn_mfma_f32_16x16x32_bf16(k1, qa[1], z, 0, 0, 0);
            st[nt] = z;
        }
        const int qq = q0 + l15;
        if (s0 + 63 > q0) {                     // wave-uniform: only causal-boundary tiles mask
#pragma unroll
            for (int nt = 0; nt < 4; nt++)
#pragma unroll
                for (int r = 0; r < 4; r++) {
                    int s = s0 + nt * 16 + quad * 4 + r;
                    st[nt][r] = (s > qq) ? NEG_BIG : st[nt][r] * sc;
                }
        } else {
#pragma unroll
            for (int nt = 0; nt < 4; nt++)
#pragma unroll
                for (int r = 0; r < 4; r++) st[nt][r] *= sc;
        }
        float mx = fmaxf(fmaxf(fmaxf(st[0][0], st[0][1]), fmaxf(st[0][2], st[0][3])),
                         fmaxf(fmaxf(st[1][0], st[1][1]), fmaxf(st[1][2], st[1][3])));
        mx = fmaxf(mx, fmaxf(fmaxf(fmaxf(st[2][0], st[2][1]), fmaxf(st[2][2], st[2][3])),
                             fmaxf(fmaxf(st[3][0], st[3][1]), fmaxf(st[3][2], st[3][3]))));
        mx = fmaxf(mx, __shfl_xor(mx, 16));
        mx = fmaxf(mx, __shfl_xor(mx, 32));
        float mn    = fmaxf(m_i, mx);
        float alpha = __builtin_amdgcn_exp2f(m_i - mn);
        m_i = mn;
        float rs = 0.f;
        bf16x4 pk[4];                           // P^T packed: r=0..3 contiguous per (nt)
#pragma unroll
        for (int nt = 0; nt < 4; nt++) {
#pragma unroll
            for (int r = 0; r < 4; r++) {
                float p = __builtin_amdgcn_exp2f(st[nt][r] - mn);   // masked -> 0
                rs += p;
                pk[nt][r] = f2b(p);
            }
        }
        rs += __shfl_xor(rs, 16);
        rs += __shfl_xor(rs, 32);
        l_i = l_i * alpha + rs;
#pragma unroll
        for (int nt = 0; nt < 4; nt++)
            *(bf16x4*)(pw + l15 * 72 + nt * 16 + quad * 4) = pk[nt];
#pragma unroll
        for (int r = 0; r < 4; r++) {
            float ar = __shfl(alpha, quad * 4 + r);
#pragma unroll
            for (int dt = 0; dt < 4; dt++) o[dt][r] *= ar;
        }
        asm volatile("s_waitcnt lgkmcnt(0)" ::: "memory");
        bf16x8 pa[2];
#pragma unroll
        for (int c = 0; c < 2; c++)
            pa[c] = *(const bf16x8*)(pw + l15 * 72 + c * 32 + quad * 8);
#pragma unroll
        for (int c = 0; c < 2; c++)
#pragma unroll
            for (int v4 = 0; v4 < 4; v4++) {
                bf16x8 vb = *(const bf16x8*)(V + (v4 * 16 + l15) * Tseq + s0 + c * 32 + quad * 8);
                o[v4] = __builtin_amdgcn_mfma_f32_16x16x32_bf16(pa[c], vb, o[v4], 0, 0, 0);
            }
    }
    // ---- flash-combine of the 4 wave partials (m,l per-lane at q=l15) ----
    if (quad == 0) ldsM[wave][l15] = m_i;
    __syncthreads();
    float Ml = fmaxf(fmaxf(ldsM[0][l15], ldsM[1][l15]), fmaxf(ldsM[2][l15], ldsM[3][l15]));
    float swl = __builtin_amdgcn_exp2f(m_i - Ml);            // empty wave: exp2(-1e30-M)=0
    l_i *= swl;
    if (quad == 0) ldsL[wave][l15] = l_i;
#pragma unroll
    for (int r = 0; r < 4; r++) {
        int row = quad * 4 + r;
        float Mr  = fmaxf(fmaxf(ldsM[0][row], ldsM[1][row]), fmaxf(ldsM[2][row], ldsM[3][row]));
        float swr = __builtin_amdgcn_exp2f(ldsM[wave][row] - Mr);
#pragma unroll
        for (int v4 = 0; v4 < 4; v4++)
            ldsO[wave][row][v4 * 16 + l15] = o[v4][r] * swr;
    }
    __syncthreads();
    const int bi = bh >> 3, hh = bh & 7;
#pragma unroll
    for (int j = 0; j < 4; j++) {
        int row = wave * 4 + j;
        float L  = ldsL[0][row] + ldsL[1][row] + ldsL[2][row] + ldsL[3][row];
        float Of = ldsO[0][row][lane] + ldsO[1][row][lane] + ldsO[2][row][lane] + ldsO[3][row][lane];
        int t   = q0 + row;
        int idx = (bi * Tseq + t) * Cdim + hh * Dh + lane;
        out1[idx] = x[idx] + Of / L;
    }
}

// ---------------- FF GEMM v2: 128x128 LDS-staged, fused bias+ReLU+residual, fp32 out ----------------
__global__ __launch_bounds__(256) void k_gemm_ff(const short* __restrict__ A, const short* __restrict__ Wt,
                                                 const float* __restrict__ bias, const float* __restrict__ res,
                                                 float* __restrict__ out) {
    const int tid = threadIdx.x;
    const int wave = tid >> 6, lane = tid & 63;
    const int quad = lane >> 4, l15 = lane & 15;
    const int m0 = blockIdx.x * 128, n0 = blockIdx.y * 128;
    const int wm = wave & 1, wn = wave >> 1;
    __shared__ __align__(16) short As[128 * 32];
    __shared__ __align__(16) short Bs[128 * 32];
    f32x4 acc[4][4];
#pragma unroll
    for (int i = 0; i < 4; i++)
#pragma unroll
        for (int j = 0; j < 4; j++) acc[i][j] = (f32x4){0.f, 0.f, 0.f, 0.f};
    const int lr = lane >> 2, lc = lane & 3;
    const short* Ag = A  + (m0 + wave * 32 + lr) * Cdim + lc * 8;
    const short* Bg = Wt + (n0 + wave * 32 + lr) * Cdim + lc * 8;
    short* Al = As + wave * 1024;
    short* Bl = Bs + wave * 1024;
    for (int kk = 0; kk < 16; kk++) {
        const int k0 = kk * 32;
        g2l16(Ag + k0,             Al);
        g2l16(Ag + 16 * Cdim + k0, Al + 512);
        g2l16(Bg + k0,             Bl);
        g2l16(Bg + 16 * Cdim + k0, Bl + 512);
        __syncthreads();
        bf16x8 a[4], w[4];
#pragma unroll
        for (int mt = 0; mt < 4; mt++) a[mt] = *(const bf16x8*)(As + (wm * 64 + mt * 16 + l15) * 32 + quad * 8);
#pragma unroll
        for (int nt = 0; nt < 4; nt++) w[nt] = *(const bf16x8*)(Bs + (wn * 64 + nt * 16 + l15) * 32 + quad * 8);
#pragma unroll
        for (int mt = 0; mt < 4; mt++)
#pragma unroll
            for (int nt = 0; nt < 4; nt++)
                acc[mt][nt] = __builtin_amdgcn_mfma_f32_16x16x32_bf16(a[mt], w[nt], acc[mt][nt], 0, 0, 0);
        __syncthreads();
    }
    const int m0w = m0 + wm * 64, n0w = n0 + wn * 64;
#pragma unroll
    for (int mt = 0; mt < 4; mt++) {
#pragma unroll
        for (int r = 0; r < 4; r++) {
            int t = m0w + mt * 16 + quad * 4 + r;
#pragma unroll
            for (int nt = 0; nt < 4; nt++) {
                int n = n0w + nt * 16 + l15;
                float fv = acc[mt][nt][r] + bias[n];
                fv = fmaxf(fv, 0.f);
                out[t * Cdim + n] = res[t * Cdim + n] + fv;
            }
        }
    }
}

extern "C" void kernel_launch(void* const* d_in, const int* in_sizes, int n_in,
                              void* d_out, int out_size, void* d_ws, size_t ws_size,
                              hipStream_t stream) {
    const float* x   = (const float*)d_in[0];
    const float* wq  = (const float*)d_in[1];
    const float* wk  = (const float*)d_in[2];
    const float* wv  = (const float*)d_in[3];
    const float* wff = (const float*)d_in[4];
    const float* bff = (const float*)d_in[5];
    const float* g1  = (const float*)d_in[6];
    const float* b1  = (const float*)d_in[7];
    const float* g2  = (const float*)d_in[8];
    const float* b2  = (const float*)d_in[9];

    char* p = (char*)d_ws;                                  // ~50 MB total scratch
    short* wqkvt = (short*)p; p += (size_t)NQKV * Cdim * 2;
    short* wfft  = (short*)p; p += (size_t)Cdim * Cdim * 2;
    short* h1    = (short*)p; p += (size_t)BT * Cdim * 2;   // reused as h2 after attention
    short* qb    = (short*)p; p += (size_t)BT * Cdim * 2;
    short* kb    = (short*)p; p += (size_t)BT * Cdim * 2;
    short* vtb   = (short*)p; p += (size_t)BT * Cdim * 2;
    float* out1  = (float*)p; p += (size_t)BT * Cdim * 4;

    hipLaunchKernelGGL(k_prep,     dim3(2304),    dim3(256), 0, stream,
                       wq, wk, wv, wff, wqkvt, wfft, x, g1, b1, h1);
    hipLaunchKernelGGL(k_gemm_qkv, dim3(64, 12),  dim3(256), 0, stream, h1, wqkvt, qb, kb, vtb);
    hipLaunchKernelGGL(k_attn,     dim3(128, 32), dim3(256), 0, stream, qb, kb, vtb, x, out1);
    hipLaunchKernelGGL(k_ln,       dim3(2048),    dim3(256), 0, stream, out1, g2, b2, h1);
    hipLaunchKernelGGL(k_gemm_ff,  dim3(64, 4),   dim3(256), 0, stream, h1, wfft, bff, out1, (float*)d_out);
}

// Round 13
// 279.449 us; speedup vs baseline: 1.4671x; 1.0194x over previous
//
#include <hip/hip_runtime.h>

#define Bsz  4
#define Tseq 2048
#define Cdim 512
#define Hn   8
#define Dh   64
#define BT   8192     // Bsz*Tseq tokens
#define NQKV 1536
#define NEG_BIG (-1e30f)

typedef __attribute__((ext_vector_type(8))) short bf16x8;  // 8 bf16 = 4 VGPRs
typedef __attribute__((ext_vector_type(4))) short bf16x4;  // 4 bf16 = 2 VGPRs
typedef __attribute__((ext_vector_type(4))) float f32x4;

__device__ __forceinline__ float b2f(short s) {
    unsigned u = ((unsigned)(unsigned short)s) << 16;
    float f; __builtin_memcpy(&f, &u, 4); return f;
}
__device__ __forceinline__ short f2b(float f) {
    unsigned u; __builtin_memcpy(&u, &f, 4);
    u = (u + 0x7fffu + ((u >> 16) & 1u)) >> 16;   // RNE
    return (short)u;
}
// async global->LDS, 16B/lane; LDS dest = wave-uniform base + lane*16
__device__ __forceinline__ void g2l16(const short* g, short* l) {
    __builtin_amdgcn_global_load_lds(
        (const __attribute__((address_space(1))) unsigned int*)(uintptr_t)g,
        (__attribute__((address_space(3))) unsigned int*)l, 16, 0, 0);
}

// ---------------- prep: fused weight transpose (blocks 0..255) + LayerNorm1 (blocks 256..2303) ----------------
__global__ __launch_bounds__(256) void k_prep(const float* __restrict__ wq, const float* __restrict__ wk,
                                              const float* __restrict__ wv, const float* __restrict__ wff,
                                              short* __restrict__ wqkvt, short* __restrict__ wfft,
                                              const float* __restrict__ x, const float* __restrict__ g,
                                              const float* __restrict__ b, short* __restrict__ out) {
    const int blk = blockIdx.x, tid = threadIdx.x;
    if (blk < 256) {
        __shared__ float ldsT[64 * 65];          // 64x64 tile, pad 65: conflict-free both phases
        if (blk < 192) {                         // QKV heads: per-head 512x64 -> 64x512
            int hm = blk >> 3, ct = blk & 7;
            int proj = hm >> 3, h = hm & 7;
            const float* w = (proj == 0) ? wq : (proj == 1 ? wk : wv);
#pragma unroll
            for (int i = 0; i < 16; i++) {
                int flat = i * 256 + tid, cc = flat >> 6, dd = flat & 63;
                ldsT[dd * 65 + cc] = w[(h * 512 + ct * 64 + cc) * 64 + dd];   // coalesced in dd
            }
            __syncthreads();
#pragma unroll
            for (int i = 0; i < 16; i++) {
                int flat = i * 256 + tid, dd = flat >> 6, cc = flat & 63;
                int n = proj * 512 + h * 64 + dd;
                wqkvt[n * 512 + ct * 64 + cc] = f2b(ldsT[dd * 65 + cc]);      // coalesced in cc
            }
        } else {                                 // FF: 512x512 -> 512x512 transposed
            int b2 = blk - 192, rt = b2 >> 3, nt8 = b2 & 7;
#pragma unroll
            for (int i = 0; i < 16; i++) {
                int flat = i * 256 + tid, cc = flat >> 6, nn = flat & 63;
                ldsT[nn * 65 + cc] = wff[(rt * 64 + cc) * 512 + nt8 * 64 + nn];
            }
            __syncthreads();
#pragma unroll
            for (int i = 0; i < 16; i++) {
                int flat = i * 256 + tid, nn = flat >> 6, cc = flat & 63;
                wfft[(nt8 * 64 + nn) * 512 + rt * 64 + cc] = f2b(ldsT[nn * 65 + cc]);
            }
        }
    } else {                                     // LayerNorm1: one wave per token row
        int row  = (blk - 256) * 4 + (tid >> 6);
        int lane = tid & 63;
        const f32x4 a0 = *(const f32x4*)(x + row * Cdim + lane * 8);
        const f32x4 a1 = *(const f32x4*)(x + row * Cdim + lane * 8 + 4);
        float v[8] = {a0[0], a0[1], a0[2], a0[3], a1[0], a1[1], a1[2], a1[3]};
        float s = 0.f, sq = 0.f;
#pragma unroll
        for (int i = 0; i < 8; i++) { s += v[i]; sq += v[i] * v[i]; }
#pragma unroll
        for (int off = 1; off < 64; off <<= 1) { s += __shfl_xor(s, off); sq += __shfl_xor(sq, off); }
        float mean = s * (1.f / 512.f);
        float var  = sq * (1.f / 512.f) - mean * mean;
        float rstd = rsqrtf(var + 1e-5f);
        const f32x4 g0 = *(const f32x4*)(g + lane * 8);
        const f32x4 g1 = *(const f32x4*)(g + lane * 8 + 4);
        const f32x4 b0 = *(const f32x4*)(b + lane * 8);
        const f32x4 b1 = *(const f32x4*)(b + lane * 8 + 4);
        float gg[8] = {g0[0], g0[1], g0[2], g0[3], g1[0], g1[1], g1[2], g1[3]};
        float bb[8] = {b0[0], b0[1], b0[2], b0[3], b1[0], b1[1], b1[2], b1[3]};
        bf16x8 o;
#pragma unroll
        for (int i = 0; i < 8; i++) o[i] = f2b((v[i] - mean) * rstd * gg[i] + bb[i]);
        *(bf16x8*)(out + row * Cdim + lane * 8) = o;
    }
}

// ---------------- LayerNorm (standalone, for LN2): fp32 in, bf16 out ----------------
__global__ __launch_bounds__(256) void k_ln(const float* __restrict__ x, const float* __restrict__ g,
                                            const float* __restrict__ b, short* __restrict__ out) {
    int row  = blockIdx.x * 4 + (threadIdx.x >> 6);
    int lane = threadIdx.x & 63;
    const f32x4 a0 = *(const f32x4*)(x + row * Cdim + lane * 8);
    const f32x4 a1 = *(const f32x4*)(x + row * Cdim + lane * 8 + 4);
    float v[8] = {a0[0], a0[1], a0[2], a0[3], a1[0], a1[1], a1[2], a1[3]};
    float s = 0.f, sq = 0.f;
#pragma unroll
    for (int i = 0; i < 8; i++) { s += v[i]; sq += v[i] * v[i]; }
#pragma unroll
    for (int off = 1; off < 64; off <<= 1) { s += __shfl_xor(s, off); sq += __shfl_xor(sq, off); }
    float mean = s * (1.f / 512.f);
    float var  = sq * (1.f / 512.f) - mean * mean;
    float rstd = rsqrtf(var + 1e-5f);
    const f32x4 g0 = *(const f32x4*)(g + lane * 8);
    const f32x4 g1 = *(const f32x4*)(g + lane * 8 + 4);
    const f32x4 b0 = *(const f32x4*)(b + lane * 8);
    const f32x4 b1 = *(const f32x4*)(b + lane * 8 + 4);
    float gg[8] = {g0[0], g0[1], g0[2], g0[3], g1[0], g1[1], g1[2], g1[3]};
    float bb[8] = {b0[0], b0[1], b0[2], b0[3], b1[0], b1[1], b1[2], b1[3]};
    bf16x8 o;
#pragma unroll
    for (int i = 0; i < 8; i++) o[i] = f2b((v[i] - mean) * rstd * gg[i] + bb[i]);
    *(bf16x8*)(out + row * Cdim + lane * 8) = o;
}

// ---------------- QKV GEMM v2: 128x128 block tile, LDS-staged via global_load_lds ----------------
__global__ __launch_bounds__(256) void k_gemm_qkv(const short* __restrict__ A, const short* __restrict__ Wt,
                                                  short* __restrict__ q, short* __restrict__ k,
                                                  short* __restrict__ vt) {
    const int tid = threadIdx.x;
    const int wave = tid >> 6, lane = tid & 63;
    const int quad = lane >> 4, l15 = lane & 15;
    const int m0 = blockIdx.x * 128, n0 = blockIdx.y * 128;
    const int wm = wave & 1, wn = wave >> 1;
    __shared__ __align__(16) short As[128 * 32];   // [row][k] 64B rows
    __shared__ __align__(16) short Bs[128 * 32];
    f32x4 acc[4][4];
#pragma unroll
    for (int i = 0; i < 4; i++)
#pragma unroll
        for (int j = 0; j < 4; j++) acc[i][j] = (f32x4){0.f, 0.f, 0.f, 0.f};
    const int lr = lane >> 2, lc = lane & 3;       // staging: row = lane/4, 16B-col = lane%4
    const short* Ag = A  + (m0 + wave * 32 + lr) * Cdim + lc * 8;
    const short* Bg = Wt + (n0 + wave * 32 + lr) * Cdim + lc * 8;
    short* Al = As + wave * 1024;                  // wave-uniform LDS dest (shorts)
    short* Bl = Bs + wave * 1024;
    for (int kk = 0; kk < 16; kk++) {
        const int k0 = kk * 32;
        g2l16(Ag + k0,             Al);
        g2l16(Ag + 16 * Cdim + k0, Al + 512);
        g2l16(Bg + k0,             Bl);
        g2l16(Bg + 16 * Cdim + k0, Bl + 512);
        __syncthreads();                           // drains vmcnt before reads
        bf16x8 a[4], w[4];
#pragma unroll
        for (int mt = 0; mt < 4; mt++) a[mt] = *(const bf16x8*)(As + (wm * 64 + mt * 16 + l15) * 32 + quad * 8);
#pragma unroll
        for (int nt = 0; nt < 4; nt++) w[nt] = *(const bf16x8*)(Bs + (wn * 64 + nt * 16 + l15) * 32 + quad * 8);
#pragma unroll
        for (int mt = 0; mt < 4; mt++)
#pragma unroll
            for (int nt = 0; nt < 4; nt++)
                acc[mt][nt] = __builtin_amdgcn_mfma_f32_16x16x32_bf16(a[mt], w[nt], acc[mt][nt], 0, 0, 0);
        __syncthreads();                           // protect tiles before next staging
    }
    // epilogue: proj block-uniform (128 | 512), head wave-uniform (n0w 64-aligned)
    const int proj = n0 >> 9;
    const int n0w  = n0 + wn * 64;
    const int hh   = (n0w & 511) >> 6;
    const int m0w  = m0 + wm * 64;
#pragma unroll
    for (int mt = 0; mt < 4; mt++) {
#pragma unroll
        for (int r = 0; r < 4; r++) {
            int t  = m0w + mt * 16 + quad * 4 + r;
            int bi = t >> 11, tt = t & 2047;
#pragma unroll
            for (int nt = 0; nt < 4; nt++) {
                int d = nt * 16 + l15;
                short val = f2b(acc[mt][nt][r]);
                if (proj == 0)      q [((bi * Hn + hh) * Tseq + tt) * Dh + d] = val;
                else if (proj == 1) k [((bi * Hn + hh) * Tseq + tt) * Dh + d] = val;
                else                vt[((bi * Hn + hh) * Dh + d) * Tseq + tt] = val;
            }
        }
    }
}

// ---------------- causal flash attention, v9: v8 + full-spread CU-balance swizzle ----------------
// Round-11 evidence: kernel time ~ max-per-CU work (skew 2.0->1.76 gave x0.91). (x+y)&127
// still leaves each CU a 32-wide qtile window (ids = c mod 256 fix x and y-parity) ->
// skew ~1.76. Odd multipliers decorrelate: each CU's 16 blocks step 106k mod 128,
// covering the full qtile range (skew ~1.08) under mod-256, chunked, or other schemes.
__global__ __launch_bounds__(256) void k_attn(const short* __restrict__ qb, const short* __restrict__ kb,
                                              const short* __restrict__ vtb, const float* __restrict__ x,
                                              float* __restrict__ out1) {
    const int wave = threadIdx.x >> 6, lane = threadIdx.x & 63;
    const int quad = lane >> 4, l15 = lane & 15;
    const int bh = blockIdx.y;
    const int qtile = (37 * blockIdx.x + 53 * blockIdx.y) & 127;   // full-spread swizzle
    const int q0 = qtile * 16;
    const short* Q = qb  + bh * Tseq * Dh;
    const short* K = kb  + bh * Tseq * Dh;
    const short* V = vtb + bh * Dh * Tseq;      // [d][s]

    __shared__ __align__(16) float ldsO[4][16][64];   // combine zones; P tiles overlay in-loop
    __shared__ float ldsM[4][16];
    __shared__ float ldsL[4][16];
    short* pw = (short*)&ldsO[0][0][0] + wave * (16 * 72);  // 16x64 P tile, stride 72

    bf16x8 qa[2];
#pragma unroll
    for (int c = 0; c < 2; c++)
        qa[c] = *(const bf16x8*)(Q + (q0 + l15) * Dh + c * 32 + quad * 8);

    f32x4 o[4];
#pragma unroll
    for (int i = 0; i < 4; i++) o[i] = (f32x4){0.f, 0.f, 0.f, 0.f};
    float m_i = NEG_BIG, l_i = 0.f;             // per-lane: this lane's q = q0 + l15

    const float sc = 0.125f * 1.44269504089f;   // scale * log2(e): softmax in exp2 domain
    const int nkt = (q0 + 79) >> 6;             // 64-key tiles covering keys <= q0+15
    for (int kt = wave; kt < nkt; kt += 4) {    // strided split-K across the 4 waves
        const int s0 = kt * 64;
        f32x4 st[4];
#pragma unroll
        for (int nt = 0; nt < 4; nt++) {
            bf16x8 k0 = *(const bf16x8*)(K + (s0 + nt * 16 + l15) * Dh + quad * 8);
            bf16x8 k1 = *(const bf16x8*)(K + (s0 + nt * 16 + l15) * Dh + 32 + quad * 8);
            f32x4 z = (f32x4){0.f, 0.f, 0.f, 0.f};
            z = __builtin_amdgcn_mfma_f32_16x16x32_bf16(k0, qa[0], z, 0, 0, 0);
            z = __builtin_amdgcn_mfma_f32_16x16x32_bf16(k1, qa[1], z, 0, 0, 0);
            st[nt] = z;
        }
        const int qq = q0 + l15;
        if (s0 + 63 > q0) {                     // wave-uniform: only causal-boundary tiles mask
#pragma unroll
            for (int nt = 0; nt < 4; nt++)
#pragma unroll
                for (int r = 0; r < 4; r++) {
                    int s = s0 + nt * 16 + quad * 4 + r;
                    st[nt][r] = (s > qq) ? NEG_BIG : st[nt][r] * sc;
                }
        } else {
#pragma unroll
            for (int nt = 0; nt < 4; nt++)
#pragma unroll
                for (int r = 0; r < 4; r++) st[nt][r] *= sc;
        }
        float mx = fmaxf(fmaxf(fmaxf(st[0][0], st[0][1]), fmaxf(st[0][2], st[0][3])),
                         fmaxf(fmaxf(st[1][0], st[1][1]), fmaxf(st[1][2], st[1][3])));
        mx = fmaxf(mx, fmaxf(fmaxf(fmaxf(st[2][0], st[2][1]), fmaxf(st[2][2], st[2][3])),
                             fmaxf(fmaxf(st[3][0], st[3][1]), fmaxf(st[3][2], st[3][3]))));
        mx = fmaxf(mx, __shfl_xor(mx, 16));
        mx = fmaxf(mx, __shfl_xor(mx, 32));
        float mn    = fmaxf(m_i, mx);
        float alpha = __builtin_amdgcn_exp2f(m_i - mn);
        m_i = mn;
        float rs = 0.f;
        bf16x4 pk[4];                           // P^T packed: r=0..3 contiguous per (nt)
#pragma unroll
        for (int nt = 0; nt < 4; nt++) {
#pragma unroll
            for (int r = 0; r < 4; r++) {
                float p = __builtin_amdgcn_exp2f(st[nt][r] - mn);   // masked -> 0
                rs += p;
                pk[nt][r] = f2b(p);
            }
        }
        rs += __shfl_xor(rs, 16);
        rs += __shfl_xor(rs, 32);
        l_i = l_i * alpha + rs;
#pragma unroll
        for (int nt = 0; nt < 4; nt++)
            *(bf16x4*)(pw + l15 * 72 + nt * 16 + quad * 4) = pk[nt];
#pragma unroll
        for (int r = 0; r < 4; r++) {
            float ar = __shfl(alpha, quad * 4 + r);
#pragma unroll
            for (int dt = 0; dt < 4; dt++) o[dt][r] *= ar;
        }
        asm volatile("s_waitcnt lgkmcnt(0)" ::: "memory");
        bf16x8 pa[2];
#pragma unroll
        for (int c = 0; c < 2; c++)
            pa[c] = *(const bf16x8*)(pw + l15 * 72 + c * 32 + quad * 8);
#pragma unroll
        for (int c = 0; c < 2; c++)
#pragma unroll
            for (int v4 = 0; v4 < 4; v4++) {
                bf16x8 vb = *(const bf16x8*)(V + (v4 * 16 + l15) * Tseq + s0 + c * 32 + quad * 8);
                o[v4] = __builtin_amdgcn_mfma_f32_16x16x32_bf16(pa[c], vb, o[v4], 0, 0, 0);
            }
    }
    // ---- flash-combine of the 4 wave partials (m,l per-lane at q=l15) ----
    if (quad == 0) ldsM[wave][l15] = m_i;
    __syncthreads();
    float Ml = fmaxf(fmaxf(ldsM[0][l15], ldsM[1][l15]), fmaxf(ldsM[2][l15], ldsM[3][l15]));
    float swl = __builtin_amdgcn_exp2f(m_i - Ml);            // empty wave: exp2(-1e30-M)=0
    l_i *= swl;
    if (quad == 0) ldsL[wave][l15] = l_i;
#pragma unroll
    for (int r = 0; r < 4; r++) {
        int row = quad * 4 + r;
        float Mr  = fmaxf(fmaxf(ldsM[0][row], ldsM[1][row]), fmaxf(ldsM[2][row], ldsM[3][row]));
        float swr = __builtin_amdgcn_exp2f(ldsM[wave][row] - Mr);
#pragma unroll
        for (int v4 = 0; v4 < 4; v4++)
            ldsO[wave][row][v4 * 16 + l15] = o[v4][r] * swr;
    }
    __syncthreads();
    const int bi = bh >> 3, hh = bh & 7;
#pragma unroll
    for (int j = 0; j < 4; j++) {
        int row = wave * 4 + j;
        float L  = ldsL[0][row] + ldsL[1][row] + ldsL[2][row] + ldsL[3][row];
        float Of = ldsO[0][row][lane] + ldsO[1][row][lane] + ldsO[2][row][lane] + ldsO[3][row][lane];
        int t   = q0 + row;
        int idx = (bi * Tseq + t) * Cdim + hh * Dh + lane;
        out1[idx] = x[idx] + Of / L;
    }
}

// ---------------- FF GEMM v2: 128x128 LDS-staged, fused bias+ReLU+residual, fp32 out ----------------
__global__ __launch_bounds__(256) void k_gemm_ff(const short* __restrict__ A, const short* __restrict__ Wt,
                                                 const float* __restrict__ bias, const float* __restrict__ res,
                                                 float* __restrict__ out) {
    const int tid = threadIdx.x;
    const int wave = tid >> 6, lane = tid & 63;
    const int quad = lane >> 4, l15 = lane & 15;
    const int m0 = blockIdx.x * 128, n0 = blockIdx.y * 128;
    const int wm = wave & 1, wn = wave >> 1;
    __shared__ __align__(16) short As[128 * 32];
    __shared__ __align__(16) short Bs[128 * 32];
    f32x4 acc[4][4];
#pragma unroll
    for (int i = 0; i < 4; i++)
#pragma unroll
        for (int j = 0; j < 4; j++) acc[i][j] = (f32x4){0.f, 0.f, 0.f, 0.f};
    const int lr = lane >> 2, lc = lane & 3;
    const short* Ag = A  + (m0 + wave * 32 + lr) * Cdim + lc * 8;
    const short* Bg = Wt + (n0 + wave * 32 + lr) * Cdim + lc * 8;
    short* Al = As + wave * 1024;
    short* Bl = Bs + wave * 1024;
    for (int kk = 0; kk < 16; kk++) {
        const int k0 = kk * 32;
        g2l16(Ag + k0,             Al);
        g2l16(Ag + 16 * Cdim + k0, Al + 512);
        g2l16(Bg + k0,             Bl);
        g2l16(Bg + 16 * Cdim + k0, Bl + 512);
        __syncthreads();
        bf16x8 a[4], w[4];
#pragma unroll
        for (int mt = 0; mt < 4; mt++) a[mt] = *(const bf16x8*)(As + (wm * 64 + mt * 16 + l15) * 32 + quad * 8);
#pragma unroll
        for (int nt = 0; nt < 4; nt++) w[nt] = *(const bf16x8*)(Bs + (wn * 64 + nt * 16 + l15) * 32 + quad * 8);
#pragma unroll
        for (int mt = 0; mt < 4; mt++)
#pragma unroll
            for (int nt = 0; nt < 4; nt++)
                acc[mt][nt] = __builtin_amdgcn_mfma_f32_16x16x32_bf16(a[mt], w[nt], acc[mt][nt], 0, 0, 0);
        __syncthreads();
    }
    const int m0w = m0 + wm * 64, n0w = n0 + wn * 64;
#pragma unroll
    for (int mt = 0; mt < 4; mt++) {
#pragma unroll
        for (int r = 0; r < 4; r++) {
            int t = m0w + mt * 16 + quad * 4 + r;
#pragma unroll
            for (int nt = 0; nt < 4; nt++) {
                int n = n0w + nt * 16 + l15;
                float fv = acc[mt][nt][r] + bias[n];
                fv = fmaxf(fv, 0.f);
                out[t * Cdim + n] = res[t * Cdim + n] + fv;
            }
        }
    }
}

extern "C" void kernel_launch(void* const* d_in, const int* in_sizes, int n_in,
                              void* d_out, int out_size, void* d_ws, size_t ws_size,
                              hipStream_t stream) {
    const float* x   = (const float*)d_in[0];
    const float* wq  = (const float*)d_in[1];
    const float* wk  = (const float*)d_in[2];
    const float* wv  = (const float*)d_in[3];
    const float* wff = (const float*)d_in[4];
    const float* bff = (const float*)d_in[5];
    const float* g1  = (const float*)d_in[6];
    const float* b1  = (const float*)d_in[7];
    const float* g2  = (const float*)d_in[8];
    const float* b2  = (const float*)d_in[9];

    char* p = (char*)d_ws;                                  // ~50 MB total scratch
    short* wqkvt = (short*)p; p += (size_t)NQKV * Cdim * 2;
    short* wfft  = (short*)p; p += (size_t)Cdim * Cdim * 2;
    short* h1    = (short*)p; p += (size_t)BT * Cdim * 2;   // reused as h2 after attention
    short* qb    = (short*)p; p += (size_t)BT * Cdim * 2;
    short* kb    = (short*)p; p += (size_t)BT * Cdim * 2;
    short* vtb   = (short*)p; p += (size_t)BT * Cdim * 2;
    float* out1  = (float*)p; p += (size_t)BT * Cdim * 4;

    hipLaunchKernelGGL(k_prep,     dim3(2304),    dim3(256), 0, stream,
                       wq, wk, wv, wff, wqkvt, wfft, x, g1, b1, h1);
    hipLaunchKernelGGL(k_gemm_qkv, dim3(64, 12),  dim3(256), 0, stream, h1, wqkvt, qb, kb, vtb);
    hipLaunchKernelGGL(k_attn,     dim3(128, 32), dim3(256), 0, stream, qb, kb, vtb, x, out1);
    hipLaunchKernelGGL(k_ln,       dim3(2048),    dim3(256), 0, stream, out1, g2, b2, h1);
    hipLaunchKernelGGL(k_gemm_ff,  dim3(64, 4),   dim3(256), 0, stream, h1, wfft, bff, out1, (float*)d_out);
}